// Round 5
// baseline (173.543 us; speedup 1.0000x reference)
//
#include <hip/hip_runtime.h>
#include <stdint.h>

// ---------------------------------------------------------------------------
// CustomGPT2MultiHeadAttention: B=4, S=1024, SI=512, D=1024, H=16, Dh=64
// Round 5: GEMMs converted to T3 minimum 2-phase double-buffered LDS
// (stage next K-tile early, 1 barrier/iter) — loads overlap MFMA.
// attn/prep unchanged from round 4.
// ---------------------------------------------------------------------------

typedef unsigned short u16;
typedef short bf16x8v __attribute__((ext_vector_type(8)));
typedef float f32x4 __attribute__((ext_vector_type(4)));

__device__ __forceinline__ u16 f2bf(float f) {
  union { float f; uint32_t u; } x; x.f = f;
  uint32_t r = x.u + 0x7FFFu + ((x.u >> 16) & 1u);   // round-to-nearest-even
  return (u16)(r >> 16);
}

// v_cvt_pk_bf16_f32: D[15:0]=bf16(a), D[31:16]=bf16(b), RNE
__device__ __forceinline__ uint32_t cvtpk(float a, float b) {
  uint32_t r;
  asm("v_cvt_pk_bf16_f32 %0, %1, %2" : "=v"(r) : "v"(a), "v"(b));
  return r;
}

// p = bit(msrc,off) ? e : 0   via sign-extended 1-bit field + AND (2 VALU)
__device__ __forceinline__ float maskand(float e, uint32_t msrc, int off) {
  uint32_t mm = (uint32_t)((int32_t)(msrc << (31 - off)) >> 31);
  union { float f; uint32_t u; } x; x.f = e; x.u &= mm; return x.f;
}

__device__ __forceinline__ void gl_lds16(const u16* g, u16* l) {
  __builtin_amdgcn_global_load_lds((const __attribute__((address_space(1))) unsigned int*)g,
                                   (__attribute__((address_space(3))) unsigned int*)l,
                                   16, 0, 0);
}

// ---------------------------------------------------------------------------
// 1) fused prep: mask bit-pack + hidden/image cast + 6-weight cast.
__global__ __launch_bounds__(256) void prep(const int* __restrict__ mk,
                                            const float4* __restrict__ hs,
                                            const float4* __restrict__ im,
                                            const float4* __restrict__ w0, const float4* __restrict__ w1,
                                            const float4* __restrict__ w2, const float4* __restrict__ w3,
                                            const float4* __restrict__ w4, const float4* __restrict__ w5,
                                            uint32_t* __restrict__ Mw,
                                            u16* __restrict__ Hb, u16* __restrict__ Ib,
                                            u16* __restrict__ Wb) {
  const int nthr = gridDim.x * 256;
  const int gid = blockIdx.x * 256 + threadIdx.x;

  for (int w = gid; w < 196608; w += nthr) {
    const int4* p = (const int4*)(mk + (size_t)w * 32);
    uint32_t bits = 0;
    #pragma unroll
    for (int c = 0; c < 8; ++c) {
      int4 v = p[c];
      bits |= (uint32_t)(v.x != 0) << (4 * c);
      bits |= (uint32_t)(v.y != 0) << (4 * c + 1);
      bits |= (uint32_t)(v.z != 0) << (4 * c + 2);
      bits |= (uint32_t)(v.w != 0) << (4 * c + 3);
    }
    Mw[w] = bits;
  }
  for (int i = gid; i < 1572864; i += nthr) {
    float4 v; u16* d;
    if (i < 1048576) { v = hs[i];            d = Hb + (size_t)i * 4; }
    else             { v = im[i - 1048576];  d = Ib + (size_t)(i - 1048576) * 4; }
    ushort4 o; o.x = f2bf(v.x); o.y = f2bf(v.y); o.z = f2bf(v.z); o.w = f2bf(v.w);
    *(ushort4*)d = o;
  }
  for (int i = gid; i < 1572864; i += nthr) {
    int w = i >> 18, off = i & 262143;
    const float4* s;
    switch (w) {
      case 0: s = w0; break; case 1: s = w1; break; case 2: s = w2; break;
      case 3: s = w3; break; case 4: s = w4; break; default: s = w5; break;
    }
    float4 v = s[off];
    ushort4 o; o.x = f2bf(v.x); o.y = f2bf(v.y); o.z = f2bf(v.z); o.w = f2bf(v.w);
    *(ushort4*)(Wb + ((size_t)w << 20) + (size_t)off * 4) = o;
  }
}

// ---------------------------------------------------------------------------
// Fused QKV GEMM, 2-phase double-buffered (T3 minimum recipe).
// 128x128 tile, BK=64, 4 waves 2x2, swizzled global_load_lds staging.
// blocks 0..767 = self (mode 4), 768..1023 = image (mode 5).
__global__ __launch_bounds__(256) void gemm_qkv(const u16* __restrict__ Hb, const u16* __restrict__ Ib,
                                                const u16* __restrict__ Wb,
                                                u16* __restrict__ Qd, u16* __restrict__ Kd,
                                                u16* __restrict__ Vd)
{
  __shared__ __align__(16) u16 As[2][128 * 64];   // 32 KB
  __shared__ __align__(16) u16 Bs[2][128 * 64];   // 32 KB
  const int bid = blockIdx.x;
  const u16 *A, *Bm;
  int bm, bn, mode;
  if (bid < 768) { mode = 4; A = Hb; Bm = Wb;
                   int y = bid / 24; bm = y * 128; bn = (bid - y * 24) * 128; }
  else           { mode = 5; A = Ib; Bm = Wb + 3 * 1048576;
                   int r = bid - 768; bm = (r >> 4) * 128; bn = (r & 15) * 128; }
  const int tid  = threadIdx.x;
  const int lane = tid & 63, wave = tid >> 6;
  const int wr = wave >> 1, wc = wave & 1;
  const int g = lane >> 4, c = lane & 15;

  f32x4 zf = {0.f, 0.f, 0.f, 0.f};
  f32x4 acc[4][4];
  #pragma unroll
  for (int mi = 0; mi < 4; ++mi)
    #pragma unroll
    for (int ni = 0; ni < 4; ++ni) acc[mi][ni] = zf;

  const int sr  = tid >> 3;          // 0..31
  const int pch = tid & 7;           // physical 16B chunk
  const int swz = (pch ^ (sr & 7)) * 8;
  const int cs  = c & 7;
  const int ldso = (tid >> 3) * 64 + pch * 8;   // base LDS elem offset for q=0

  // prologue: stage K-tile 0 into buffer 0
  #pragma unroll
  for (int q = 0; q < 4; ++q) {
    gl_lds16(A  + (size_t)(bm + q * 32 + sr) * 1024 + swz, &As[0][q * 2048 + ldso]);
    gl_lds16(Bm + (size_t)(bn + q * 32 + sr) * 1024 + swz, &Bs[0][q * 2048 + ldso]);
  }
  __syncthreads();

  int cur = 0;
  for (int t = 0; t < 16; ++t) {
    if (t < 15) {
      const int k1 = (t + 1) * 64;
      #pragma unroll
      for (int q = 0; q < 4; ++q) {
        gl_lds16(A  + (size_t)(bm + q * 32 + sr) * 1024 + k1 + swz, &As[cur ^ 1][q * 2048 + ldso]);
        gl_lds16(Bm + (size_t)(bn + q * 32 + sr) * 1024 + k1 + swz, &Bs[cur ^ 1][q * 2048 + ldso]);
      }
    }
    const u16* as = &As[cur][0];
    const u16* bs = &Bs[cur][0];
    #pragma unroll
    for (int ks = 0; ks < 2; ++ks) {
      bf16x8v af[4], bfr[4];
      #pragma unroll
      for (int mi = 0; mi < 4; ++mi)
        af[mi] = *(const bf16x8v*)&as[(wr * 64 + mi * 16 + c) * 64 + (((ks * 4 + g) ^ cs)) * 8];
      #pragma unroll
      for (int ni = 0; ni < 4; ++ni)
        bfr[ni] = *(const bf16x8v*)&bs[(wc * 64 + ni * 16 + c) * 64 + (((ks * 4 + g) ^ cs)) * 8];
      #pragma unroll
      for (int mi = 0; mi < 4; ++mi)
        #pragma unroll
        for (int ni = 0; ni < 4; ++ni)
          acc[mi][ni] = __builtin_amdgcn_mfma_f32_16x16x32_bf16(af[mi], bfr[ni], acc[mi][ni], 0, 0, 0);
    }
    __syncthreads();   // drains stage vmcnt + orders buffer reuse
    cur ^= 1;
  }

  // epilogue: C row = 4*g + j, col = c
  #pragma unroll
  for (int mi = 0; mi < 4; ++mi) {
    #pragma unroll
    for (int ni = 0; ni < 4; ++ni) {
      #pragma unroll
      for (int j = 0; j < 4; ++j) {
        int gm = bm + wr * 64 + mi * 16 + 4 * g + j;
        int gn = bn + wc * 64 + ni * 16 + c;
        float v = acc[mi][ni][j];
        if (mode == 4) {
          int b_ = gm >> 10, s_ = gm & 1023;
          if (gn < 1024)      Qd[(size_t)gm * 1024 + gn] = f2bf(v * 0.18033688011112042f);
          else if (gn < 2048) Kd[(size_t)(b_ * 1536 + s_) * 1024 + (gn - 1024)] = f2bf(v);
          else                Vd[(size_t)(b_ * 1024 + (gn - 2048)) * 1536 + s_] = f2bf(v);
        } else {
          int b_ = gm >> 9, s_ = gm & 511;
          if (gn < 1024) Kd[(size_t)(b_ * 1536 + 1024 + s_) * 1024 + gn] = f2bf(v);
          else           Vd[(size_t)(b_ * 1024 + (gn - 1024)) * 1536 + 1024 + s_] = f2bf(v);
        }
      }
    }
  }
}

// out-proj GEMM, 2-phase double-buffered: M=4096 N=1024 K=1024, fp32 out
__global__ __launch_bounds__(256) void gemm_out(const u16* __restrict__ A, const u16* __restrict__ Bm,
                                                float* __restrict__ Cout)
{
  __shared__ __align__(16) u16 As[2][128 * 64];
  __shared__ __align__(16) u16 Bs[2][128 * 64];
  const int tid  = threadIdx.x;
  const int lane = tid & 63, wave = tid >> 6;
  const int wr = wave >> 1, wc = wave & 1;
  const int g = lane >> 4, c = lane & 15;
  const int bm = blockIdx.y * 128;
  const int bn = blockIdx.x * 128;

  f32x4 zf = {0.f, 0.f, 0.f, 0.f};
  f32x4 acc[4][4];
  #pragma unroll
  for (int mi = 0; mi < 4; ++mi)
    #pragma unroll
    for (int ni = 0; ni < 4; ++ni) acc[mi][ni] = zf;

  const int sr  = tid >> 3;
  const int pch = tid & 7;
  const int swz = (pch ^ (sr & 7)) * 8;
  const int cs  = c & 7;
  const int ldso = sr * 64 + pch * 8;

  #pragma unroll
  for (int q = 0; q < 4; ++q) {
    gl_lds16(A  + (size_t)(bm + q * 32 + sr) * 1024 + swz, &As[0][q * 2048 + ldso]);
    gl_lds16(Bm + (size_t)(bn + q * 32 + sr) * 1024 + swz, &Bs[0][q * 2048 + ldso]);
  }
  __syncthreads();

  int cur = 0;
  for (int t = 0; t < 16; ++t) {
    if (t < 15) {
      const int k1 = (t + 1) * 64;
      #pragma unroll
      for (int q = 0; q < 4; ++q) {
        gl_lds16(A  + (size_t)(bm + q * 32 + sr) * 1024 + k1 + swz, &As[cur ^ 1][q * 2048 + ldso]);
        gl_lds16(Bm + (size_t)(bn + q * 32 + sr) * 1024 + k1 + swz, &Bs[cur ^ 1][q * 2048 + ldso]);
      }
    }
    const u16* as = &As[cur][0];
    const u16* bs = &Bs[cur][0];
    #pragma unroll
    for (int ks = 0; ks < 2; ++ks) {
      bf16x8v af[4], bfr[4];
      #pragma unroll
      for (int mi = 0; mi < 4; ++mi)
        af[mi] = *(const bf16x8v*)&as[(wr * 64 + mi * 16 + c) * 64 + (((ks * 4 + g) ^ cs)) * 8];
      #pragma unroll
      for (int ni = 0; ni < 4; ++ni)
        bfr[ni] = *(const bf16x8v*)&bs[(wc * 64 + ni * 16 + c) * 64 + (((ks * 4 + g) ^ cs)) * 8];
      #pragma unroll
      for (int mi = 0; mi < 4; ++mi)
        #pragma unroll
        for (int ni = 0; ni < 4; ++ni)
          acc[mi][ni] = __builtin_amdgcn_mfma_f32_16x16x32_bf16(af[mi], bfr[ni], acc[mi][ni], 0, 0, 0);
    }
    __syncthreads();
    cur ^= 1;
  }

  #pragma unroll
  for (int mi = 0; mi < 4; ++mi)
    #pragma unroll
    for (int ni = 0; ni < 4; ++ni)
      #pragma unroll
      for (int j = 0; j < 4; ++j) {
        int gm = bm + wr * 64 + mi * 16 + 4 * g + j;
        int gn = bn + wc * 64 + ni * 16 + c;
        Cout[(size_t)gm * 1024 + gn] = acc[mi][ni][j];
      }
}

// ---------------------------------------------------------------------------
// flash attention, swapped QK^T, max-free softmax (unchanged from round 4)
__global__ __launch_bounds__(256) void attn_kernel(const u16* __restrict__ Q, const u16* __restrict__ Kc,
                                                   const u16* __restrict__ Vt,
                                                   const uint32_t* __restrict__ Mw,
                                                   u16* __restrict__ AO)
{
  const int bid = blockIdx.x;
  const int grp = bid & 63;           // (b,h) group; XCD = bid%8 = grp%8
  const int qt  = bid >> 6;
  const int h = grp & 15, b = grp >> 4;
  const int q0 = qt * 64;
  const int tid = threadIdx.x, lane = tid & 63, wave = tid >> 6;
  const int g = lane >> 4, c = lane & 15;
  const int qw = q0 + wave * 16;

  __shared__ __align__(16) u16 Ks[64 * 64];      // 8 KB
  __shared__ __align__(16) u16 Vs[64 * 64];      // 8 KB  [d][l]
  __shared__ __align__(16) u16 Ps[4][16 * 72];   // 9 KB  per-wave P, padded

  bf16x8v qf0, qf1;
  {
    const u16* qp = Q + (size_t)(b * 1024 + qw + c) * 1024 + h * 64 + g * 8;
    qf0 = *(const bf16x8v*)qp;
    qf1 = *(const bf16x8v*)(qp + 32);
  }
  f32x4 zf = {0.f, 0.f, 0.f, 0.f};
  f32x4 O[4];                       // O^T frag: [d=dt*16+4g+j][q=c]
  float l = 0.f;                    // per-lane partial denominator
  #pragma unroll
  for (int dt = 0; dt < 4; ++dt) O[dt] = zf;

  const int sr  = tid >> 3;         // 0..31
  const int pch = tid & 7;
  const int swz = (pch ^ (sr & 7)) * 8;   // write-side XOR swizzle
  const int cs  = c & 7;
  const u16* Kbase = Kc + (size_t)(b * 1536) * 1024 + h * 64;
  const u16* Vbase = Vt + (size_t)(b * 1024 + h * 64) * 1536;
  const uint32_t* mrow = Mw + (size_t)(b * 1024 + qw + c) * 48;

  bf16x8v kr0, kr1, vr0, vr1;
  kr0 = *(const bf16x8v*)(Kbase + (size_t)sr * 1024 + pch * 8);
  kr1 = *(const bf16x8v*)(Kbase + (size_t)(32 + sr) * 1024 + pch * 8);
  vr0 = *(const bf16x8v*)(Vbase + (size_t)sr * 1536 + pch * 8);
  vr1 = *(const bf16x8v*)(Vbase + (size_t)(32 + sr) * 1536 + pch * 8);
  *(bf16x8v*)&Ks[sr * 64 + swz]        = kr0;
  *(bf16x8v*)&Ks[(32 + sr) * 64 + swz] = kr1;
  *(bf16x8v*)&Vs[sr * 64 + swz]        = vr0;
  *(bf16x8v*)&Vs[(32 + sr) * 64 + swz] = vr1;
  __syncthreads();

  for (int kt = 0; kt < 24; ++kt) {
    if (kt < 23) {
      const int ln = (kt + 1) * 64;
      kr0 = *(const bf16x8v*)(Kbase + (size_t)(ln + sr) * 1024 + pch * 8);
      kr1 = *(const bf16x8v*)(Kbase + (size_t)(ln + 32 + sr) * 1024 + pch * 8);
      vr0 = *(const bf16x8v*)(Vbase + (size_t)sr * 1536 + ln + pch * 8);
      vr1 = *(const bf16x8v*)(Vbase + (size_t)(32 + sr) * 1536 + ln + pch * 8);
    }
    uint2 mwv = *(const uint2*)(mrow + kt * 2);

    f32x4 s[4];
    __builtin_amdgcn_s_setprio(1);
    #pragma unroll
    for (int nt = 0; nt < 4; ++nt) {
      const u16* kr = &Ks[(nt * 16 + c) * 64];
      bf16x8v k0 = *(const bf16x8v*)&kr[(g ^ cs) * 8];
      bf16x8v k1 = *(const bf16x8v*)&kr[((4 + g) ^ cs) * 8];
      f32x4 z = zf;
      z = __builtin_amdgcn_mfma_f32_16x16x32_bf16(k0, qf0, z, 0, 0, 0);
      z = __builtin_amdgcn_mfma_f32_16x16x32_bf16(k1, qf1, z, 0, 0, 0);
      s[nt] = z;
    }
    __builtin_amdgcn_s_setprio(0);

    uint64_t mq = (((uint64_t)mwv.y << 32) | (uint64_t)mwv.x) >> (4 * g);
    uint32_t mlo = (uint32_t)mq, mhi = (uint32_t)(mq >> 32);
    #pragma unroll
    for (int nt = 0; nt < 4; ++nt) {
      uint32_t msrc = (nt < 2) ? mlo : mhi;
      #pragma unroll
      for (int j = 0; j < 4; ++j) {
        float e = exp2f(s[nt][j]);
        float p = maskand(e, msrc, 16 * (nt & 1) + j);
        s[nt][j] = p;
        l += p;
      }
    }

    u16* pw = &Ps[wave][0];
    #pragma unroll
    for (int nt = 0; nt < 4; ++nt) {
      uint2 pk2;
      pk2.x = cvtpk(s[nt][0], s[nt][1]);
      pk2.y = cvtpk(s[nt][2], s[nt][3]);
      *(uint2*)&pw[c * 72 + nt * 16 + g * 4] = pk2;
    }
    bf16x8v pb0 = *(const bf16x8v*)&pw[c * 72 + g * 8];
    bf16x8v pb1 = *(const bf16x8v*)&pw[c * 72 + 32 + g * 8];
    __builtin_amdgcn_s_setprio(1);
    #pragma unroll
    for (int dt = 0; dt < 4; ++dt) {
      const u16* vr = &Vs[(dt * 16 + c) * 64];
      bf16x8v v0 = *(const bf16x8v*)&vr[(g ^ cs) * 8];
      bf16x8v v1 = *(const bf16x8v*)&vr[((4 + g) ^ cs) * 8];
      O[dt] = __builtin_amdgcn_mfma_f32_16x16x32_bf16(v0, pb0, O[dt], 0, 0, 0);
      O[dt] = __builtin_amdgcn_mfma_f32_16x16x32_bf16(v1, pb1, O[dt], 0, 0, 0);
    }
    __builtin_amdgcn_s_setprio(0);

    __syncthreads();                 // all waves done READING Ks/Vs
    if (kt < 23) {
      *(bf16x8v*)&Ks[sr * 64 + swz]        = kr0;
      *(bf16x8v*)&Ks[(32 + sr) * 64 + swz] = kr1;
      *(bf16x8v*)&Vs[sr * 64 + swz]        = vr0;
      *(bf16x8v*)&Vs[(32 + sr) * 64 + swz] = vr1;
      __syncthreads();
    }
  }

  float r = l;
  r += __shfl_xor(r, 16);
  r += __shfl_xor(r, 32);
  float inv = 1.f / r;
  size_t ro = (size_t)(b * 1024 + qw + c) * 1024 + h * 64;
  #pragma unroll
  for (int dt = 0; dt < 4; ++dt) {
    uint2 st;
    st.x = cvtpk(O[dt][0] * inv, O[dt][1] * inv);
    st.y = cvtpk(O[dt][2] * inv, O[dt][3] * inv);
    *(uint2*)&AO[ro + dt * 16 + 4 * g] = st;
  }
}

// ---------------------------------------------------------------------------
extern "C" void kernel_launch(void* const* d_in, const int* in_sizes, int n_in,
                              void* d_out, int out_size, void* d_ws, size_t ws_size,
                              hipStream_t stream) {
  (void)in_sizes; (void)n_in; (void)out_size; (void)ws_size;
  const float* hs = (const float*)d_in[0];
  const float* im = (const float*)d_in[1];
  const int*   mk = (const int*)d_in[2];
  const float* wq = (const float*)d_in[3];
  const float* wk = (const float*)d_in[4];
  const float* wv = (const float*)d_in[5];
  const float* uk = (const float*)d_in[6];
  const float* uv = (const float*)d_in[7];
  const float* wo = (const float*)d_in[8];

  char* ws = (char*)d_ws;
  u16* Hb  = (u16*)(ws + 0);          //  8,388,608 B  hidden bf16; reused as attn-out
  u16* Ib  = (u16*)(ws + 8388608);    //  4,194,304 B  image bf16
  u16* Wb  = (u16*)(ws + 12582912);   // 12,582,912 B  weights bf16 (wq wk wv uk uv wo)
  u16* Qb  = (u16*)(ws + 25165824);   //  8,388,608 B  Q token-major [4096][1024] (pre-scaled)
  u16* Kb  = (u16*)(ws + 33554432);   // 12,582,912 B  K concat [4][1536][1024]
  u16* Vtb = (u16*)(ws + 46137344);   // 12,582,912 B  V transposed [4][1024][1536]
  uint32_t* Mw = (uint32_t*)(ws + 58720256); // 786,432 B packed mask
  // total ws: 59,506,688 B

  prep<<<2048, 256, 0, stream>>>(mk, (const float4*)hs, (const float4*)im,
                                 (const float4*)wq, (const float4*)wk, (const float4*)wv,
                                 (const float4*)uk, (const float4*)uv, (const float4*)wo,
                                 Mw, Hb, Ib, Wb);
  gemm_qkv<<<1024, 256, 0, stream>>>(Hb, Ib, Wb, Qb, Kb, Vtb);
  attn_kernel<<<1024, 256, 0, stream>>>(Qb, Kb, Vtb, Mw, Hb);
  gemm_out<<<dim3(8, 32), 256, 0, stream>>>(Hb, Wb + 5 * 1048576, (float*)d_out);
}

// Round 6
// 167.610 us; speedup vs baseline: 1.0354x; 1.0354x over previous
//
#include <hip/hip_runtime.h>
#include <stdint.h>

// ---------------------------------------------------------------------------
// CustomGPT2MultiHeadAttention: B=4, S=1024, SI=512, D=1024, H=16, Dh=64
// Round 6: GEMMs rebuilt as 3-region software pipeline (lookahead-2 K-tiles,
// counted s_waitcnt vmcnt(4), raw s_barrier, 512 thr / 8 waves, 96 KB LDS).
// Loads stay in flight ACROSS barriers (T4). attn/prep = round-4 known-good.
// ---------------------------------------------------------------------------

typedef unsigned short u16;
typedef short bf16x8v __attribute__((ext_vector_type(8)));
typedef float f32x4 __attribute__((ext_vector_type(4)));

__device__ __forceinline__ u16 f2bf(float f) {
  union { float f; uint32_t u; } x; x.f = f;
  uint32_t r = x.u + 0x7FFFu + ((x.u >> 16) & 1u);   // round-to-nearest-even
  return (u16)(r >> 16);
}

// v_cvt_pk_bf16_f32: D[15:0]=bf16(a), D[31:16]=bf16(b), RNE
__device__ __forceinline__ uint32_t cvtpk(float a, float b) {
  uint32_t r;
  asm("v_cvt_pk_bf16_f32 %0, %1, %2" : "=v"(r) : "v"(a), "v"(b));
  return r;
}

// p = bit(msrc,off) ? e : 0   via sign-extended 1-bit field + AND (2 VALU)
__device__ __forceinline__ float maskand(float e, uint32_t msrc, int off) {
  uint32_t mm = (uint32_t)((int32_t)(msrc << (31 - off)) >> 31);
  union { float f; uint32_t u; } x; x.f = e; x.u &= mm; return x.f;
}

__device__ __forceinline__ void gl_lds16(const u16* g, u16* l) {
  __builtin_amdgcn_global_load_lds((const __attribute__((address_space(1))) unsigned int*)g,
                                   (__attribute__((address_space(3))) unsigned int*)l,
                                   16, 0, 0);
}

// ---------------------------------------------------------------------------
// 1) fused prep: mask bit-pack + hidden/image cast + 6-weight cast.
__global__ __launch_bounds__(256) void prep(const int* __restrict__ mk,
                                            const float4* __restrict__ hs,
                                            const float4* __restrict__ im,
                                            const float4* __restrict__ w0, const float4* __restrict__ w1,
                                            const float4* __restrict__ w2, const float4* __restrict__ w3,
                                            const float4* __restrict__ w4, const float4* __restrict__ w5,
                                            uint32_t* __restrict__ Mw,
                                            u16* __restrict__ Hb, u16* __restrict__ Ib,
                                            u16* __restrict__ Wb) {
  const int nthr = gridDim.x * 256;
  const int gid = blockIdx.x * 256 + threadIdx.x;

  for (int w = gid; w < 196608; w += nthr) {
    const int4* p = (const int4*)(mk + (size_t)w * 32);
    uint32_t bits = 0;
    #pragma unroll
    for (int c = 0; c < 8; ++c) {
      int4 v = p[c];
      bits |= (uint32_t)(v.x != 0) << (4 * c);
      bits |= (uint32_t)(v.y != 0) << (4 * c + 1);
      bits |= (uint32_t)(v.z != 0) << (4 * c + 2);
      bits |= (uint32_t)(v.w != 0) << (4 * c + 3);
    }
    Mw[w] = bits;
  }
  for (int i = gid; i < 1572864; i += nthr) {
    float4 v; u16* d;
    if (i < 1048576) { v = hs[i];            d = Hb + (size_t)i * 4; }
    else             { v = im[i - 1048576];  d = Ib + (size_t)(i - 1048576) * 4; }
    ushort4 o; o.x = f2bf(v.x); o.y = f2bf(v.y); o.z = f2bf(v.z); o.w = f2bf(v.w);
    *(ushort4*)d = o;
  }
  for (int i = gid; i < 1572864; i += nthr) {
    int w = i >> 18, off = i & 262143;
    const float4* s;
    switch (w) {
      case 0: s = w0; break; case 1: s = w1; break; case 2: s = w2; break;
      case 3: s = w3; break; case 4: s = w4; break; default: s = w5; break;
    }
    float4 v = s[off];
    ushort4 o; o.x = f2bf(v.x); o.y = f2bf(v.y); o.z = f2bf(v.z); o.w = f2bf(v.w);
    *(ushort4*)(Wb + ((size_t)w << 20) + (size_t)off * 4) = o;
  }
}

// ---------------------------------------------------------------------------
// Pipelined GEMM core: C[m,n] = sum_k A[m,k]*B[n,k], K=1024, tile 128x128,
// BK=64, 512 threads = 8 waves (2Mx4N), 3 LDS regions/matrix (96 KB),
// lookahead-2 staging, counted vmcnt(4), raw s_barrier (1 per K-step).
//
// Pipeline proof: iter t stages tile t+2 (4 gl_lds/thread). At iter-t end,
// outstanding = tile(t+1)'s 4 + tile(t+2)'s 4; vmcnt(4) drains tile t+1
// (needed by iter t+1's ds_reads), leaves tile t+2 in flight. Region
// (t+2)%3 was last read in iter t-1 (before the barrier the staging
// follows), so the async landing is race-free. Tail: t>=14 -> vmcnt(0).

#define GEMM_STAGE(Ap, Bp, reg, kt)                                                        \
  do {                                                                                     \
    gl_lds16((Ap) + (size_t)(bm + sr) * 1024 + (kt) * 64 + swz,                            \
             &As[(reg) * 8192 + sr * 64 + pch * 8]);                                       \
    gl_lds16((Ap) + (size_t)(bm + 64 + sr) * 1024 + (kt) * 64 + swz,                       \
             &As[(reg) * 8192 + (64 + sr) * 64 + pch * 8]);                                \
    gl_lds16((Bp) + (size_t)(bn + sr) * 1024 + (kt) * 64 + swz,                            \
             &Bs[(reg) * 8192 + sr * 64 + pch * 8]);                                       \
    gl_lds16((Bp) + (size_t)(bn + 64 + sr) * 1024 + (kt) * 64 + swz,                       \
             &Bs[(reg) * 8192 + (64 + sr) * 64 + pch * 8]);                                \
  } while (0)

#define GEMM_PIPELINE(Ap, Bp)                                                              \
  GEMM_STAGE(Ap, Bp, 0, 0);                                                                \
  GEMM_STAGE(Ap, Bp, 1, 1);                                                                \
  asm volatile("s_waitcnt vmcnt(4)" ::: "memory");                                         \
  __builtin_amdgcn_s_barrier();                                                            \
  __builtin_amdgcn_sched_barrier(0);                                                       \
  {                                                                                        \
    int rc = 0;                                                                            \
    for (int t = 0; t < 16; ++t) {                                                         \
      int rs = rc + 2; if (rs >= 3) rs -= 3;                                               \
      if (t < 14) GEMM_STAGE(Ap, Bp, rs, t + 2);                                           \
      const u16* as = &As[rc * 8192];                                                      \
      const u16* bs = &Bs[rc * 8192];                                                      \
      __builtin_amdgcn_s_setprio(1);                                                       \
      _Pragma("unroll")                                                                    \
      for (int ks = 0; ks < 2; ++ks) {                                                     \
        bf16x8v af[4], bfr[2];                                                             \
        _Pragma("unroll")                                                                  \
        for (int mi = 0; mi < 4; ++mi)                                                     \
          af[mi] = *(const bf16x8v*)&as[(wr * 64 + mi * 16 + c) * 64 + ((ks * 4 + g) ^ cs) * 8]; \
        _Pragma("unroll")                                                                  \
        for (int ni = 0; ni < 2; ++ni)                                                     \
          bfr[ni] = *(const bf16x8v*)&bs[(wc * 32 + ni * 16 + c) * 64 + ((ks * 4 + g) ^ cs) * 8]; \
        _Pragma("unroll")                                                                  \
        for (int mi = 0; mi < 4; ++mi)                                                     \
          _Pragma("unroll")                                                                \
          for (int ni = 0; ni < 2; ++ni)                                                   \
            acc[mi][ni] = __builtin_amdgcn_mfma_f32_16x16x32_bf16(af[mi], bfr[ni], acc[mi][ni], 0, 0, 0); \
      }                                                                                    \
      __builtin_amdgcn_s_setprio(0);                                                       \
      if (t < 14) { asm volatile("s_waitcnt vmcnt(4)" ::: "memory"); }                     \
      else        { asm volatile("s_waitcnt vmcnt(0)" ::: "memory"); }                     \
      __builtin_amdgcn_s_barrier();                                                        \
      __builtin_amdgcn_sched_barrier(0);                                                   \
      rc = (rc + 1 == 3) ? 0 : rc + 1;                                                     \
    }                                                                                      \
  }

// Fused QKV GEMM: blocks 0..767 = self (mode 4), 768..1023 = image (mode 5).
__global__ __launch_bounds__(512) void gemm_qkv(const u16* __restrict__ Hb, const u16* __restrict__ Ib,
                                                const u16* __restrict__ Wb,
                                                u16* __restrict__ Qd, u16* __restrict__ Kd,
                                                u16* __restrict__ Vd)
{
  __shared__ __align__(16) u16 As[3 * 128 * 64];   // 48 KB
  __shared__ __align__(16) u16 Bs[3 * 128 * 64];   // 48 KB
  const int bid = blockIdx.x;
  const u16 *A, *Bm;
  int bm, bn, mode;
  if (bid < 768) { mode = 4; A = Hb; Bm = Wb;
                   int y = bid / 24; bm = y * 128; bn = (bid - y * 24) * 128; }
  else           { mode = 5; A = Ib; Bm = Wb + 3 * 1048576;
                   int r = bid - 768; bm = (r >> 4) * 128; bn = (r & 15) * 128; }
  const int tid  = threadIdx.x;
  const int lane = tid & 63, wave = tid >> 6;
  const int wr = wave >> 2, wc = wave & 3;        // 2M x 4N waves; wave owns 64x32
  const int g = lane >> 4, c = lane & 15;

  f32x4 zf = {0.f, 0.f, 0.f, 0.f};
  f32x4 acc[4][2];
  #pragma unroll
  for (int mi = 0; mi < 4; ++mi)
    #pragma unroll
    for (int ni = 0; ni < 2; ++ni) acc[mi][ni] = zf;

  const int sr  = tid >> 3;          // 0..63
  const int pch = tid & 7;           // physical 16B chunk
  const int swz = (pch ^ (sr & 7)) * 8;
  const int cs  = c & 7;

  GEMM_PIPELINE(A, Bm)

  // epilogue: C row = 4*g + j, col = c
  #pragma unroll
  for (int mi = 0; mi < 4; ++mi) {
    #pragma unroll
    for (int ni = 0; ni < 2; ++ni) {
      #pragma unroll
      for (int j = 0; j < 4; ++j) {
        int gm = bm + wr * 64 + mi * 16 + 4 * g + j;
        int gn = bn + wc * 32 + ni * 16 + c;
        float v = acc[mi][ni][j];
        if (mode == 4) {
          int b_ = gm >> 10, s_ = gm & 1023;
          if (gn < 1024)      Qd[(size_t)gm * 1024 + gn] = f2bf(v * 0.18033688011112042f);
          else if (gn < 2048) Kd[(size_t)(b_ * 1536 + s_) * 1024 + (gn - 1024)] = f2bf(v);
          else                Vd[(size_t)(b_ * 1024 + (gn - 2048)) * 1536 + s_] = f2bf(v);
        } else {
          int b_ = gm >> 9, s_ = gm & 511;
          if (gn < 1024) Kd[(size_t)(b_ * 1536 + 1024 + s_) * 1024 + gn] = f2bf(v);
          else           Vd[(size_t)(b_ * 1024 + (gn - 1024)) * 1536 + 1024 + s_] = f2bf(v);
        }
      }
    }
  }
}

// out-proj GEMM: M=4096 N=1024 K=1024, fp32 out, same pipeline
__global__ __launch_bounds__(512) void gemm_out(const u16* __restrict__ A, const u16* __restrict__ Bm,
                                                float* __restrict__ Cout)
{
  __shared__ __align__(16) u16 As[3 * 128 * 64];
  __shared__ __align__(16) u16 Bs[3 * 128 * 64];
  const int tid  = threadIdx.x;
  const int lane = tid & 63, wave = tid >> 6;
  const int wr = wave >> 2, wc = wave & 3;
  const int g = lane >> 4, c = lane & 15;
  const int bm = blockIdx.y * 128;
  const int bn = blockIdx.x * 128;

  f32x4 zf = {0.f, 0.f, 0.f, 0.f};
  f32x4 acc[4][2];
  #pragma unroll
  for (int mi = 0; mi < 4; ++mi)
    #pragma unroll
    for (int ni = 0; ni < 2; ++ni) acc[mi][ni] = zf;

  const int sr  = tid >> 3;
  const int pch = tid & 7;
  const int swz = (pch ^ (sr & 7)) * 8;
  const int cs  = c & 7;

  GEMM_PIPELINE(A, Bm)

  #pragma unroll
  for (int mi = 0; mi < 4; ++mi)
    #pragma unroll
    for (int ni = 0; ni < 2; ++ni)
      #pragma unroll
      for (int j = 0; j < 4; ++j) {
        int gm = bm + wr * 64 + mi * 16 + 4 * g + j;
        int gn = bn + wc * 32 + ni * 16 + c;
        Cout[(size_t)gm * 1024 + gn] = acc[mi][ni][j];
      }
}

// ---------------------------------------------------------------------------
// flash attention, swapped QK^T, max-free softmax (round-4 known-good)
__global__ __launch_bounds__(256) void attn_kernel(const u16* __restrict__ Q, const u16* __restrict__ Kc,
                                                   const u16* __restrict__ Vt,
                                                   const uint32_t* __restrict__ Mw,
                                                   u16* __restrict__ AO)
{
  const int bid = blockIdx.x;
  const int grp = bid & 63;           // (b,h) group; XCD = bid%8 = grp%8
  const int qt  = bid >> 6;
  const int h = grp & 15, b = grp >> 4;
  const int q0 = qt * 64;
  const int tid = threadIdx.x, lane = tid & 63, wave = tid >> 6;
  const int g = lane >> 4, c = lane & 15;
  const int qw = q0 + wave * 16;

  __shared__ __align__(16) u16 Ks[64 * 64];      // 8 KB
  __shared__ __align__(16) u16 Vs[64 * 64];      // 8 KB  [d][l]
  __shared__ __align__(16) u16 Ps[4][16 * 72];   // 9 KB  per-wave P, padded

  bf16x8v qf0, qf1;
  {
    const u16* qp = Q + (size_t)(b * 1024 + qw + c) * 1024 + h * 64 + g * 8;
    qf0 = *(const bf16x8v*)qp;
    qf1 = *(const bf16x8v*)(qp + 32);
  }
  f32x4 zf = {0.f, 0.f, 0.f, 0.f};
  f32x4 O[4];                       // O^T frag: [d=dt*16+4g+j][q=c]
  float l = 0.f;                    // per-lane partial denominator
  #pragma unroll
  for (int dt = 0; dt < 4; ++dt) O[dt] = zf;

  const int sr  = tid >> 3;         // 0..31
  const int pch = tid & 7;
  const int swz = (pch ^ (sr & 7)) * 8;   // write-side XOR swizzle
  const int cs  = c & 7;
  const u16* Kbase = Kc + (size_t)(b * 1536) * 1024 + h * 64;
  const u16* Vbase = Vt + (size_t)(b * 1024 + h * 64) * 1536;
  const uint32_t* mrow = Mw + (size_t)(b * 1024 + qw + c) * 48;

  bf16x8v kr0, kr1, vr0, vr1;
  kr0 = *(const bf16x8v*)(Kbase + (size_t)sr * 1024 + pch * 8);
  kr1 = *(const bf16x8v*)(Kbase + (size_t)(32 + sr) * 1024 + pch * 8);
  vr0 = *(const bf16x8v*)(Vbase + (size_t)sr * 1536 + pch * 8);
  vr1 = *(const bf16x8v*)(Vbase + (size_t)(32 + sr) * 1536 + pch * 8);
  *(bf16x8v*)&Ks[sr * 64 + swz]        = kr0;
  *(bf16x8v*)&Ks[(32 + sr) * 64 + swz] = kr1;
  *(bf16x8v*)&Vs[sr * 64 + swz]        = vr0;
  *(bf16x8v*)&Vs[(32 + sr) * 64 + swz] = vr1;
  __syncthreads();

  for (int kt = 0; kt < 24; ++kt) {
    if (kt < 23) {
      const int ln = (kt + 1) * 64;
      kr0 = *(const bf16x8v*)(Kbase + (size_t)(ln + sr) * 1024 + pch * 8);
      kr1 = *(const bf16x8v*)(Kbase + (size_t)(ln + 32 + sr) * 1024 + pch * 8);
      vr0 = *(const bf16x8v*)(Vbase + (size_t)sr * 1536 + ln + pch * 8);
      vr1 = *(const bf16x8v*)(Vbase + (size_t)(32 + sr) * 1536 + ln + pch * 8);
    }
    uint2 mwv = *(const uint2*)(mrow + kt * 2);

    f32x4 s[4];
    __builtin_amdgcn_s_setprio(1);
    #pragma unroll
    for (int nt = 0; nt < 4; ++nt) {
      const u16* kr = &Ks[(nt * 16 + c) * 64];
      bf16x8v k0 = *(const bf16x8v*)&kr[(g ^ cs) * 8];
      bf16x8v k1 = *(const bf16x8v*)&kr[((4 + g) ^ cs) * 8];
      f32x4 z = zf;
      z = __builtin_amdgcn_mfma_f32_16x16x32_bf16(k0, qf0, z, 0, 0, 0);
      z = __builtin_amdgcn_mfma_f32_16x16x32_bf16(k1, qf1, z, 0, 0, 0);
      s[nt] = z;
    }
    __builtin_amdgcn_s_setprio(0);

    uint64_t mq = (((uint64_t)mwv.y << 32) | (uint64_t)mwv.x) >> (4 * g);
    uint32_t mlo = (uint32_t)mq, mhi = (uint32_t)(mq >> 32);
    #pragma unroll
    for (int nt = 0; nt < 4; ++nt) {
      uint32_t msrc = (nt < 2) ? mlo : mhi;
      #pragma unroll
      for (int j = 0; j < 4; ++j) {
        float e = exp2f(s[nt][j]);
        float p = maskand(e, msrc, 16 * (nt & 1) + j);
        s[nt][j] = p;
        l += p;
      }
    }

    u16* pw = &Ps[wave][0];
    #pragma unroll
    for (int nt = 0; nt < 4; ++nt) {
      uint2 pk2;
      pk2.x = cvtpk(s[nt][0], s[nt][1]);
      pk2.y = cvtpk(s[nt][2], s[nt][3]);
      *(uint2*)&pw[c * 72 + nt * 16 + g * 4] = pk2;
    }
    bf16x8v pb0 = *(const bf16x8v*)&pw[c * 72 + g * 8];
    bf16x8v pb1 = *(const bf16x8v*)&pw[c * 72 + 32 + g * 8];
    __builtin_amdgcn_s_setprio(1);
    #pragma unroll
    for (int dt = 0; dt < 4; ++dt) {
      const u16* vr = &Vs[(dt * 16 + c) * 64];
      bf16x8v v0 = *(const bf16x8v*)&vr[(g ^ cs) * 8];
      bf16x8v v1 = *(const bf16x8v*)&vr[((4 + g) ^ cs) * 8];
      O[dt] = __builtin_amdgcn_mfma_f32_16x16x32_bf16(v0, pb0, O[dt], 0, 0, 0);
      O[dt] = __builtin_amdgcn_mfma_f32_16x16x32_bf16(v1, pb1, O[dt], 0, 0, 0);
    }
    __builtin_amdgcn_s_setprio(0);

    __syncthreads();                 // all waves done READING Ks/Vs
    if (kt < 23) {
      *(bf16x8v*)&Ks[sr * 64 + swz]        = kr0;
      *(bf16x8v*)&Ks[(32 + sr) * 64 + swz] = kr1;
      *(bf16x8v*)&Vs[sr * 64 + swz]        = vr0;
      *(bf16x8v*)&Vs[(32 + sr) * 64 + swz] = vr1;
      __syncthreads();
    }
  }

  float r = l;
  r += __shfl_xor(r, 16);
  r += __shfl_xor(r, 32);
  float inv = 1.f / r;
  size_t ro = (size_t)(b * 1024 + qw + c) * 1024 + h * 64;
  #pragma unroll
  for (int dt = 0; dt < 4; ++dt) {
    uint2 st;
    st.x = cvtpk(O[dt][0] * inv, O[dt][1] * inv);
    st.y = cvtpk(O[dt][2] * inv, O[dt][3] * inv);
    *(uint2*)&AO[ro + dt * 16 + 4 * g] = st;
  }
}

// ---------------------------------------------------------------------------
extern "C" void kernel_launch(void* const* d_in, const int* in_sizes, int n_in,
                              void* d_out, int out_size, void* d_ws, size_t ws_size,
                              hipStream_t stream) {
  (void)in_sizes; (void)n_in; (void)out_size; (void)ws_size;
  const float* hs = (const float*)d_in[0];
  const float* im = (const float*)d_in[1];
  const int*   mk = (const int*)d_in[2];
  const float* wq = (const float*)d_in[3];
  const float* wk = (const float*)d_in[4];
  const float* wv = (const float*)d_in[5];
  const float* uk = (const float*)d_in[6];
  const float* uv = (const float*)d_in[7];
  const float* wo = (const float*)d_in[8];

  char* ws = (char*)d_ws;
  u16* Hb  = (u16*)(ws + 0);          //  8,388,608 B  hidden bf16; reused as attn-out
  u16* Ib  = (u16*)(ws + 8388608);    //  4,194,304 B  image bf16
  u16* Wb  = (u16*)(ws + 12582912);   // 12,582,912 B  weights bf16 (wq wk wv uk uv wo)
  u16* Qb  = (u16*)(ws + 25165824);   //  8,388,608 B  Q token-major [4096][1024] (pre-scaled)
  u16* Kb  = (u16*)(ws + 33554432);   // 12,582,912 B  K concat [4][1536][1024]
  u16* Vtb = (u16*)(ws + 46137344);   // 12,582,912 B  V transposed [4][1024][1536]
  uint32_t* Mw = (uint32_t*)(ws + 58720256); // 786,432 B packed mask
  // total ws: 59,506,688 B

  prep<<<2048, 256, 0, stream>>>(mk, (const float4*)hs, (const float4*)im,
                                 (const float4*)wq, (const float4*)wk, (const float4*)wv,
                                 (const float4*)uk, (const float4*)uv, (const float4*)wo,
                                 Mw, Hb, Ib, Wb);
  gemm_qkv<<<1024, 512, 0, stream>>>(Hb, Ib, Wb, Qb, Kb, Vtb);
  attn_kernel<<<1024, 256, 0, stream>>>(Qb, Kb, Vtb, Mw, Hb);
  gemm_out<<<dim3(8, 32), 512, 0, stream>>>(Hb, Wb + 5 * 1048576, (float*)d_out);
}

// Round 7
// 165.644 us; speedup vs baseline: 1.0477x; 1.0119x over previous
//
#include <hip/hip_runtime.h>
#include <stdint.h>

// ---------------------------------------------------------------------------
// CustomGPT2MultiHeadAttention: B=4, S=1024, SI=512, D=1024, H=16, Dh=64
// Round 7: gemm_qkv rebuilt as the 256x256 8-phase template (m201 geometry):
// 512 thr / 8 waves (2Mx4N), BK=64, 128 KB LDS double-buffer, per-K-tile
// 4 fine phases {ds_read subtile | stage 1 half-tile | barrier | setprio+
// 16 MFMA | barrier}, ONE counted vmcnt(2) per K-tile (never 0 till tail).
// gemm_out reverted to round-4 known-good. attn/prep unchanged.
// ---------------------------------------------------------------------------

typedef unsigned short u16;
typedef short bf16x8v __attribute__((ext_vector_type(8)));
typedef float f32x4 __attribute__((ext_vector_type(4)));

__device__ __forceinline__ u16 f2bf(float f) {
  union { float f; uint32_t u; } x; x.f = f;
  uint32_t r = x.u + 0x7FFFu + ((x.u >> 16) & 1u);   // round-to-nearest-even
  return (u16)(r >> 16);
}

// v_cvt_pk_bf16_f32: D[15:0]=bf16(a), D[31:16]=bf16(b), RNE
__device__ __forceinline__ uint32_t cvtpk(float a, float b) {
  uint32_t r;
  asm("v_cvt_pk_bf16_f32 %0, %1, %2" : "=v"(r) : "v"(a), "v"(b));
  return r;
}

// p = bit(msrc,off) ? e : 0   via sign-extended 1-bit field + AND (2 VALU)
__device__ __forceinline__ float maskand(float e, uint32_t msrc, int off) {
  uint32_t mm = (uint32_t)((int32_t)(msrc << (31 - off)) >> 31);
  union { float f; uint32_t u; } x; x.f = e; x.u &= mm; return x.f;
}

__device__ __forceinline__ void gl_lds16(const u16* g, u16* l) {
  __builtin_amdgcn_global_load_lds((const __attribute__((address_space(1))) unsigned int*)g,
                                   (__attribute__((address_space(3))) unsigned int*)l,
                                   16, 0, 0);
}

// ---------------------------------------------------------------------------
// 1) fused prep: mask bit-pack + hidden/image cast + 6-weight cast.
__global__ __launch_bounds__(256) void prep(const int* __restrict__ mk,
                                            const float4* __restrict__ hs,
                                            const float4* __restrict__ im,
                                            const float4* __restrict__ w0, const float4* __restrict__ w1,
                                            const float4* __restrict__ w2, const float4* __restrict__ w3,
                                            const float4* __restrict__ w4, const float4* __restrict__ w5,
                                            uint32_t* __restrict__ Mw,
                                            u16* __restrict__ Hb, u16* __restrict__ Ib,
                                            u16* __restrict__ Wb) {
  const int nthr = gridDim.x * 256;
  const int gid = blockIdx.x * 256 + threadIdx.x;

  for (int w = gid; w < 196608; w += nthr) {
    const int4* p = (const int4*)(mk + (size_t)w * 32);
    uint32_t bits = 0;
    #pragma unroll
    for (int c = 0; c < 8; ++c) {
      int4 v = p[c];
      bits |= (uint32_t)(v.x != 0) << (4 * c);
      bits |= (uint32_t)(v.y != 0) << (4 * c + 1);
      bits |= (uint32_t)(v.z != 0) << (4 * c + 2);
      bits |= (uint32_t)(v.w != 0) << (4 * c + 3);
    }
    Mw[w] = bits;
  }
  for (int i = gid; i < 1572864; i += nthr) {
    float4 v; u16* d;
    if (i < 1048576) { v = hs[i];            d = Hb + (size_t)i * 4; }
    else             { v = im[i - 1048576];  d = Ib + (size_t)(i - 1048576) * 4; }
    ushort4 o; o.x = f2bf(v.x); o.y = f2bf(v.y); o.z = f2bf(v.z); o.w = f2bf(v.w);
    *(ushort4*)d = o;
  }
  for (int i = gid; i < 1572864; i += nthr) {
    int w = i >> 18, off = i & 262143;
    const float4* s;
    switch (w) {
      case 0: s = w0; break; case 1: s = w1; break; case 2: s = w2; break;
      case 3: s = w3; break; case 4: s = w4; break; default: s = w5; break;
    }
    float4 v = s[off];
    ushort4 o; o.x = f2bf(v.x); o.y = f2bf(v.y); o.z = f2bf(v.z); o.w = f2bf(v.w);
    *(ushort4*)(Wb + ((size_t)w << 20) + (size_t)off * 4) = o;
  }
}

// ---------------------------------------------------------------------------
// Fused QKV GEMM, 256x256 8-phase template. C[m,n] = sum_k A[m,k]*B[n,k].
// Grid: 256 blocks = 192 self (16x12) + 64 image (8x8). 512 thr, 8 waves.
// Wave (wr,wc): output rows wr*128+0..127, cols wc*64+0..63; acc[8][4].
// K=1024 -> 16 K-tiles of BK=64; LDS: A,B each 2 buf x [256][64] (128 KB).
// Per K-tile kt (buffer b=kt&1), staging kt+1 into b^1, one half-tile/phase:
//   P0: stage A-half0(kt+1); vmcnt(2) [keeps those 2 in flight]; s_barrier;
//       read B-frags(8)+A-frags(4); MFMA x16; s_barrier
//   P1..P3: read A-frags(4); stage next half; s_barrier; MFMA x16; s_barrier
// Race ledger: buffer b^1 half H's overwriting stage issues >=1 barrier after
// H's last ds_read completed (consumed by prior kt's MFMA). vmcnt(2)+barrier
// at P0 guarantees all waves' kt-loads landed before any kt ds_read.
__global__ __launch_bounds__(512, 2) void gemm_qkv(const u16* __restrict__ Hb, const u16* __restrict__ Ib,
                                                   const u16* __restrict__ Wb,
                                                   u16* __restrict__ Qd, u16* __restrict__ Kd,
                                                   u16* __restrict__ Vd)
{
  __shared__ __align__(16) u16 As[2 * 16384];   // 64 KB
  __shared__ __align__(16) u16 Bs[2 * 16384];   // 64 KB
  const int bid = blockIdx.x;
  const u16 *A, *Bm;
  int bm, bn, mode;
  if (bid < 192) { mode = 4; A = Hb; Bm = Wb;
                   bm = (bid / 12) * 256; bn = (bid % 12) * 256; }
  else           { mode = 5; A = Ib; Bm = Wb + 3 * 1048576;
                   int r = bid - 192; bm = (r >> 3) * 256; bn = (r & 7) * 256; }
  const int tid = threadIdx.x, lane = tid & 63, wave = tid >> 6;
  const int wr = wave >> 2, wc = wave & 3;      // 2M x 4N
  const int g = lane >> 4, c = lane & 15, cs = c & 7;
  const int srow = tid >> 3;                    // 0..63
  const int pch  = tid & 7;
  const int swz  = (pch ^ (srow & 7)) * 8;      // XOR-chunk swizzle (involution)

  f32x4 zf = {0.f, 0.f, 0.f, 0.f};
  f32x4 acc[8][4];
  #pragma unroll
  for (int f = 0; f < 8; ++f)
    #pragma unroll
    for (int nf = 0; nf < 4; ++nf) acc[f][nf] = zf;

  // stage one half-tile (128 rows x 64 k) = 2 gl_lds per thread.
  // LDS dest: buf*16384 + half*8192 + row*64 + pch*8 == wave-uniform base
  // + lane*16B (verified), so gl_lds lane-ordering matches.
  #define STG(GP, LDSA, base, buf, half, kt)                                        \
    do {                                                                            \
      _Pragma("unroll")                                                             \
      for (int j_ = 0; j_ < 2; ++j_) {                                              \
        int row_ = j_ * 64 + srow;                                                  \
        gl_lds16((GP) + (size_t)((base) + (half) * 128 + row_) * 1024 + (kt) * 64 + swz, \
                 &(LDSA)[(buf) * 16384 + (half) * 8192 + row_ * 64 + pch * 8]);     \
      }                                                                             \
    } while (0)

  // prologue: K-tile 0, all 4 half-tiles (8 loads/thread)
  STG(A,  As, bm, 0, 0, 0);
  STG(A,  As, bm, 0, 1, 0);
  STG(Bm, Bs, bn, 0, 0, 0);
  STG(Bm, Bs, bn, 0, 1, 0);

  for (int kt = 0; kt < 16; ++kt) {
    const int bc = (kt & 1) * 16384;
    const int bx = (kt + 1) & 1;
    // ---- P0: stage A-half0 of kt+1, counted wait, all-waves barrier ----
    if (kt < 15) {
      STG(A, As, bm, bx, 0, kt + 1);
      asm volatile("s_waitcnt vmcnt(2)" ::: "memory");
    } else {
      asm volatile("s_waitcnt vmcnt(0)" ::: "memory");
    }
    asm volatile("s_barrier" ::: "memory");

    // B-frags for the whole K-tile (8 ds_read_b128)
    bf16x8v Bf[4][2];
    #pragma unroll
    for (int nf = 0; nf < 4; ++nf)
      #pragma unroll
      for (int ks = 0; ks < 2; ++ks)
        Bf[nf][ks] = *(const bf16x8v*)&Bs[bc + (wc * 64 + nf * 16 + c) * 64 + ((ks * 4 + g) ^ cs) * 8];

    #pragma unroll
    for (int p = 0; p < 4; ++p) {
      // A-frags for this phase's 32-row slab (4 ds_read_b128)
      bf16x8v Af[2][2];
      #pragma unroll
      for (int i = 0; i < 2; ++i)
        #pragma unroll
        for (int ks = 0; ks < 2; ++ks)
          Af[i][ks] = *(const bf16x8v*)&As[bc + (wr * 128 + (p * 2 + i) * 16 + c) * 64 + ((ks * 4 + g) ^ cs) * 8];
      if (kt < 15) {
        if (p == 1)      STG(A,  As, bm, bx, 1, kt + 1);
        else if (p == 2) STG(Bm, Bs, bn, bx, 0, kt + 1);
        else if (p == 3) STG(Bm, Bs, bn, bx, 1, kt + 1);
      }
      if (p > 0) asm volatile("s_barrier" ::: "memory");
      __builtin_amdgcn_s_setprio(1);
      #pragma unroll
      for (int i = 0; i < 2; ++i)
        #pragma unroll
        for (int nf = 0; nf < 4; ++nf)
          #pragma unroll
          for (int ks = 0; ks < 2; ++ks)
            acc[p * 2 + i][nf] =
              __builtin_amdgcn_mfma_f32_16x16x32_bf16(Af[i][ks], Bf[nf][ks], acc[p * 2 + i][nf], 0, 0, 0);
      __builtin_amdgcn_s_setprio(0);
      asm volatile("s_barrier" ::: "memory");
    }
  }
  #undef STG

  // epilogue: C row = 4*g + j, col = c
  #pragma unroll
  for (int f = 0; f < 8; ++f) {
    #pragma unroll
    for (int nf = 0; nf < 4; ++nf) {
      #pragma unroll
      for (int j = 0; j < 4; ++j) {
        int gm = bm + wr * 128 + f * 16 + 4 * g + j;
        int gn = bn + wc * 64 + nf * 16 + c;
        float v = acc[f][nf][j];
        if (mode == 4) {
          int b_ = gm >> 10, s_ = gm & 1023;
          if (gn < 1024)      Qd[(size_t)gm * 1024 + gn] = f2bf(v * 0.18033688011112042f);
          else if (gn < 2048) Kd[(size_t)(b_ * 1536 + s_) * 1024 + (gn - 1024)] = f2bf(v);
          else                Vd[(size_t)(b_ * 1024 + (gn - 2048)) * 1536 + s_] = f2bf(v);
        } else {
          int b_ = gm >> 9, s_ = gm & 511;
          if (gn < 1024) Kd[(size_t)(b_ * 1536 + 1024 + s_) * 1024 + gn] = f2bf(v);
          else           Vd[(size_t)(b_ * 1024 + (gn - 1024)) * 1536 + 1024 + s_] = f2bf(v);
        }
      }
    }
  }
}

// ---------------------------------------------------------------------------
// out-proj GEMM (round-4 known-good): 128x128 tile, BK=64, 256 thr, 4 waves,
// single-buffer 2-barrier loop. M=4096 N=1024 K=1024, fp32 out.
__global__ __launch_bounds__(256) void gemm_out(const u16* __restrict__ A, const u16* __restrict__ Bm,
                                                float* __restrict__ Cout)
{
  __shared__ __align__(16) u16 As[128 * 64];
  __shared__ __align__(16) u16 Bs[128 * 64];
  const int tid  = threadIdx.x;
  const int lane = tid & 63, wave = tid >> 6;
  const int wr = wave >> 1, wc = wave & 1;
  const int g = lane >> 4, c = lane & 15;
  const int bm = blockIdx.y * 128;
  const int bn = blockIdx.x * 128;

  f32x4 zf = {0.f, 0.f, 0.f, 0.f};
  f32x4 acc[4][4];
  #pragma unroll
  for (int mi = 0; mi < 4; ++mi)
    #pragma unroll
    for (int ni = 0; ni < 4; ++ni) acc[mi][ni] = zf;

  const int sr  = tid >> 3;
  const int pch = tid & 7;
  const int swz = (pch ^ (sr & 7)) * 8;
  const int cs  = c & 7;

  for (int k0 = 0; k0 < 1024; k0 += 64) {
    #pragma unroll
    for (int q = 0; q < 4; ++q)
      gl_lds16(A + (size_t)(bm + q * 32 + sr) * 1024 + k0 + swz, &As[(q * 32 + sr) * 64 + pch * 8]);
    #pragma unroll
    for (int q = 0; q < 4; ++q)
      gl_lds16(Bm + (size_t)(bn + q * 32 + sr) * 1024 + k0 + swz, &Bs[(q * 32 + sr) * 64 + pch * 8]);
    __syncthreads();

    #pragma unroll
    for (int ks = 0; ks < 2; ++ks) {
      bf16x8v af[4], bfr[4];
      #pragma unroll
      for (int mi = 0; mi < 4; ++mi)
        af[mi] = *(const bf16x8v*)&As[(wr * 64 + mi * 16 + c) * 64 + (((ks * 4 + g) ^ cs)) * 8];
      #pragma unroll
      for (int ni = 0; ni < 4; ++ni)
        bfr[ni] = *(const bf16x8v*)&Bs[(wc * 64 + ni * 16 + c) * 64 + (((ks * 4 + g) ^ cs)) * 8];
      #pragma unroll
      for (int mi = 0; mi < 4; ++mi)
        #pragma unroll
        for (int ni = 0; ni < 4; ++ni)
          acc[mi][ni] = __builtin_amdgcn_mfma_f32_16x16x32_bf16(af[mi], bfr[ni], acc[mi][ni], 0, 0, 0);
    }
    __syncthreads();
  }

  #pragma unroll
  for (int mi = 0; mi < 4; ++mi)
    #pragma unroll
    for (int ni = 0; ni < 4; ++ni)
      #pragma unroll
      for (int j = 0; j < 4; ++j) {
        int gm = bm + wr * 64 + mi * 16 + 4 * g + j;
        int gn = bn + wc * 64 + ni * 16 + c;
        Cout[(size_t)gm * 1024 + gn] = acc[mi][ni][j];
      }
}

// ---------------------------------------------------------------------------
// flash attention, swapped QK^T, max-free softmax (round-4 known-good)
__global__ __launch_bounds__(256) void attn_kernel(const u16* __restrict__ Q, const u16* __restrict__ Kc,
                                                   const u16* __restrict__ Vt,
                                                   const uint32_t* __restrict__ Mw,
                                                   u16* __restrict__ AO)
{
  const int bid = blockIdx.x;
  const int grp = bid & 63;           // (b,h) group; XCD = bid%8 = grp%8
  const int qt  = bid >> 6;
  const int h = grp & 15, b = grp >> 4;
  const int q0 = qt * 64;
  const int tid = threadIdx.x, lane = tid & 63, wave = tid >> 6;
  const int g = lane >> 4, c = lane & 15;
  const int qw = q0 + wave * 16;

  __shared__ __align__(16) u16 Ks[64 * 64];      // 8 KB
  __shared__ __align__(16) u16 Vs[64 * 64];      // 8 KB  [d][l]
  __shared__ __align__(16) u16 Ps[4][16 * 72];   // 9 KB  per-wave P, padded

  bf16x8v qf0, qf1;
  {
    const u16* qp = Q + (size_t)(b * 1024 + qw + c) * 1024 + h * 64 + g * 8;
    qf0 = *(const bf16x8v*)qp;
    qf1 = *(const bf16x8v*)(qp + 32);
  }
  f32x4 zf = {0.f, 0.f, 0.f, 0.f};
  f32x4 O[4];                       // O^T frag: [d=dt*16+4g+j][q=c]
  float l = 0.f;                    // per-lane partial denominator
  #pragma unroll
  for (int dt = 0; dt < 4; ++dt) O[dt] = zf;

  const int sr  = tid >> 3;         // 0..31
  const int pch = tid & 7;
  const int swz = (pch ^ (sr & 7)) * 8;   // write-side XOR swizzle
  const int cs  = c & 7;
  const u16* Kbase = Kc + (size_t)(b * 1536) * 1024 + h * 64;
  const u16* Vbase = Vt + (size_t)(b * 1024 + h * 64) * 1536;
  const uint32_t* mrow = Mw + (size_t)(b * 1024 + qw + c) * 48;

  bf16x8v kr0, kr1, vr0, vr1;
  kr0 = *(const bf16x8v*)(Kbase + (size_t)sr * 1024 + pch * 8);
  kr1 = *(const bf16x8v*)(Kbase + (size_t)(32 + sr) * 1024 + pch * 8);
  vr0 = *(const bf16x8v*)(Vbase + (size_t)sr * 1536 + pch * 8);
  vr1 = *(const bf16x8v*)(Vbase + (size_t)(32 + sr) * 1536 + pch * 8);
  *(bf16x8v*)&Ks[sr * 64 + swz]        = kr0;
  *(bf16x8v*)&Ks[(32 + sr) * 64 + swz] = kr1;
  *(bf16x8v*)&Vs[sr * 64 + swz]        = vr0;
  *(bf16x8v*)&Vs[(32 + sr) * 64 + swz] = vr1;
  __syncthreads();

  for (int kt = 0; kt < 24; ++kt) {
    if (kt < 23) {
      const int ln = (kt + 1) * 64;
      kr0 = *(const bf16x8v*)(Kbase + (size_t)(ln + sr) * 1024 + pch * 8);
      kr1 = *(const bf16x8v*)(Kbase + (size_t)(ln + 32 + sr) * 1024 + pch * 8);
      vr0 = *(const bf16x8v*)(Vbase + (size_t)sr * 1536 + ln + pch * 8);
      vr1 = *(const bf16x8v*)(Vbase + (size_t)(32 + sr) * 1536 + ln + pch * 8);
    }
    uint2 mwv = *(const uint2*)(mrow + kt * 2);

    f32x4 s[4];
    __builtin_amdgcn_s_setprio(1);
    #pragma unroll
    for (int nt = 0; nt < 4; ++nt) {
      const u16* kr = &Ks[(nt * 16 + c) * 64];
      bf16x8v k0 = *(const bf16x8v*)&kr[(g ^ cs) * 8];
      bf16x8v k1 = *(const bf16x8v*)&kr[((4 + g) ^ cs) * 8];
      f32x4 z = zf;
      z = __builtin_amdgcn_mfma_f32_16x16x32_bf16(k0, qf0, z, 0, 0, 0);
      z = __builtin_amdgcn_mfma_f32_16x16x32_bf16(k1, qf1, z, 0, 0, 0);
      s[nt] = z;
    }
    __builtin_amdgcn_s_setprio(0);

    uint64_t mq = (((uint64_t)mwv.y << 32) | (uint64_t)mwv.x) >> (4 * g);
    uint32_t mlo = (uint32_t)mq, mhi = (uint32_t)(mq >> 32);
    #pragma unroll
    for (int nt = 0; nt < 4; ++nt) {
      uint32_t msrc = (nt < 2) ? mlo : mhi;
      #pragma unroll
      for (int j = 0; j < 4; ++j) {
        float e = exp2f(s[nt][j]);
        float p = maskand(e, msrc, 16 * (nt & 1) + j);
        s[nt][j] = p;
        l += p;
      }
    }

    u16* pw = &Ps[wave][0];
    #pragma unroll
    for (int nt = 0; nt < 4; ++nt) {
      uint2 pk2;
      pk2.x = cvtpk(s[nt][0], s[nt][1]);
      pk2.y = cvtpk(s[nt][2], s[nt][3]);
      *(uint2*)&pw[c * 72 + nt * 16 + g * 4] = pk2;
    }
    bf16x8v pb0 = *(const bf16x8v*)&pw[c * 72 + g * 8];
    bf16x8v pb1 = *(const bf16x8v*)&pw[c * 72 + 32 + g * 8];
    __builtin_amdgcn_s_setprio(1);
    #pragma unroll
    for (int dt = 0; dt < 4; ++dt) {
      const u16* vr = &Vs[(dt * 16 + c) * 64];
      bf16x8v v0 = *(const bf16x8v*)&vr[(g ^ cs) * 8];
      bf16x8v v1 = *(const bf16x8v*)&vr[((4 + g) ^ cs) * 8];
      O[dt] = __builtin_amdgcn_mfma_f32_16x16x32_bf16(v0, pb0, O[dt], 0, 0, 0);
      O[dt] = __builtin_amdgcn_mfma_f32_16x16x32_bf16(v1, pb1, O[dt], 0, 0, 0);
    }
    __builtin_amdgcn_s_setprio(0);

    __syncthreads();                 // all waves done READING Ks/Vs
    if (kt < 23) {
      *(bf16x8v*)&Ks[sr * 64 + swz]        = kr0;
      *(bf16x8v*)&Ks[(32 + sr) * 64 + swz] = kr1;
      *(bf16x8v*)&Vs[sr * 64 + swz]        = vr0;
      *(bf16x8v*)&Vs[(32 + sr) * 64 + swz] = vr1;
      __syncthreads();
    }
  }

  float r = l;
  r += __shfl_xor(r, 16);
  r += __shfl_xor(r, 32);
  float inv = 1.f / r;
  size_t ro = (size_t)(b * 1024 + qw + c) * 1024 + h * 64;
  #pragma unroll
  for (int dt = 0; dt < 4; ++dt) {
    uint2 st;
    st.x = cvtpk(O[dt][0] * inv, O[dt][1] * inv);
    st.y = cvtpk(O[dt][2] * inv, O[dt][3] * inv);
    *(uint2*)&AO[ro + dt * 16 + 4 * g] = st;
  }
}

// ---------------------------------------------------------------------------
extern "C" void kernel_launch(void* const* d_in, const int* in_sizes, int n_in,
                              void* d_out, int out_size, void* d_ws, size_t ws_size,
                              hipStream_t stream) {
  (void)in_sizes; (void)n_in; (void)out_size; (void)ws_size;
  const float* hs = (const float*)d_in[0];
  const float* im = (const float*)d_in[1];
  const int*   mk = (const int*)d_in[2];
  const float* wq = (const float*)d_in[3];
  const float* wk = (const float*)d_in[4];
  const float* wv = (const float*)d_in[5];
  const float* uk = (const float*)d_in[6];
  const float* uv = (const float*)d_in[7];
  const float* wo = (const float*)d_in[8];

  char* ws = (char*)d_ws;
  u16* Hb  = (u16*)(ws + 0);          //  8,388,608 B  hidden bf16; reused as attn-out
  u16* Ib  = (u16*)(ws + 8388608);    //  4,194,304 B  image bf16
  u16* Wb  = (u16*)(ws + 12582912);   // 12,582,912 B  weights bf16 (wq wk wv uk uv wo)
  u16* Qb  = (u16*)(ws + 25165824);   //  8,388,608 B  Q token-major [4096][1024] (pre-scaled)
  u16* Kb  = (u16*)(ws + 33554432);   // 12,582,912 B  K concat [4][1536][1024]
  u16* Vtb = (u16*)(ws + 46137344);   // 12,582,912 B  V transposed [4][1024][1536]
  uint32_t* Mw = (uint32_t*)(ws + 58720256); // 786,432 B packed mask
  // total ws: 59,506,688 B

  prep<<<2048, 256, 0, stream>>>(mk, (const float4*)hs, (const float4*)im,
                                 (const float4*)wq, (const float4*)wk, (const float4*)wv,
                                 (const float4*)uk, (const float4*)uv, (const float4*)wo,
                                 Mw, Hb, Ib, Wb);
  gemm_qkv<<<256, 512, 0, stream>>>(Hb, Ib, Wb, Qb, Kb, Vtb);
  attn_kernel<<<1024, 256, 0, stream>>>(Qb, Kb, Vtb, Mw, Hb);
  gemm_out<<<dim3(8, 32), 256, 0, stream>>>(Hb, Wb + 5 * 1048576, (float*)d_out);
}

// Round 8
// 165.365 us; speedup vs baseline: 1.0495x; 1.0017x over previous
//
#include <hip/hip_runtime.h>
#include <stdint.h>

// ---------------------------------------------------------------------------
// CustomGPT2MultiHeadAttention: B=4, S=1024, SI=512, D=1024, H=16, Dh=64
// Round 8: GEMMs = 256² (qkv) / 128² (out) double-buffer with FULL-TILE
// prefetch slack: stage ALL of tile kt+1 at top of tile kt, vmcnt(8) (drains
// only tile kt, keeps kt+1 in flight), ONE barrier, whole-tile compute with
// no intra-tile barriers, ONE end barrier. attn/prep = round-4 known-good.
// ---------------------------------------------------------------------------

typedef unsigned short u16;
typedef short bf16x8v __attribute__((ext_vector_type(8)));
typedef float f32x4 __attribute__((ext_vector_type(4)));

__device__ __forceinline__ u16 f2bf(float f) {
  union { float f; uint32_t u; } x; x.f = f;
  uint32_t r = x.u + 0x7FFFu + ((x.u >> 16) & 1u);   // round-to-nearest-even
  return (u16)(r >> 16);
}

// v_cvt_pk_bf16_f32: D[15:0]=bf16(a), D[31:16]=bf16(b), RNE
__device__ __forceinline__ uint32_t cvtpk(float a, float b) {
  uint32_t r;
  asm("v_cvt_pk_bf16_f32 %0, %1, %2" : "=v"(r) : "v"(a), "v"(b));
  return r;
}

// p = bit(msrc,off) ? e : 0   via sign-extended 1-bit field + AND (2 VALU)
__device__ __forceinline__ float maskand(float e, uint32_t msrc, int off) {
  uint32_t mm = (uint32_t)((int32_t)(msrc << (31 - off)) >> 31);
  union { float f; uint32_t u; } x; x.f = e; x.u &= mm; return x.f;
}

__device__ __forceinline__ void gl_lds16(const u16* g, u16* l) {
  __builtin_amdgcn_global_load_lds((const __attribute__((address_space(1))) unsigned int*)g,
                                   (__attribute__((address_space(3))) unsigned int*)l,
                                   16, 0, 0);
}

// ---------------------------------------------------------------------------
// 1) fused prep: mask bit-pack + hidden/image cast + 6-weight cast.
__global__ __launch_bounds__(256) void prep(const int* __restrict__ mk,
                                            const float4* __restrict__ hs,
                                            const float4* __restrict__ im,
                                            const float4* __restrict__ w0, const float4* __restrict__ w1,
                                            const float4* __restrict__ w2, const float4* __restrict__ w3,
                                            const float4* __restrict__ w4, const float4* __restrict__ w5,
                                            uint32_t* __restrict__ Mw,
                                            u16* __restrict__ Hb, u16* __restrict__ Ib,
                                            u16* __restrict__ Wb) {
  const int nthr = gridDim.x * 256;
  const int gid = blockIdx.x * 256 + threadIdx.x;

  for (int w = gid; w < 196608; w += nthr) {
    const int4* p = (const int4*)(mk + (size_t)w * 32);
    uint32_t bits = 0;
    #pragma unroll
    for (int c = 0; c < 8; ++c) {
      int4 v = p[c];
      bits |= (uint32_t)(v.x != 0) << (4 * c);
      bits |= (uint32_t)(v.y != 0) << (4 * c + 1);
      bits |= (uint32_t)(v.z != 0) << (4 * c + 2);
      bits |= (uint32_t)(v.w != 0) << (4 * c + 3);
    }
    Mw[w] = bits;
  }
  for (int i = gid; i < 1572864; i += nthr) {
    float4 v; u16* d;
    if (i < 1048576) { v = hs[i];            d = Hb + (size_t)i * 4; }
    else             { v = im[i - 1048576];  d = Ib + (size_t)(i - 1048576) * 4; }
    ushort4 o; o.x = f2bf(v.x); o.y = f2bf(v.y); o.z = f2bf(v.z); o.w = f2bf(v.w);
    *(ushort4*)d = o;
  }
  for (int i = gid; i < 1572864; i += nthr) {
    int w = i >> 18, off = i & 262143;
    const float4* s;
    switch (w) {
      case 0: s = w0; break; case 1: s = w1; break; case 2: s = w2; break;
      case 3: s = w3; break; case 4: s = w4; break; default: s = w5; break;
    }
    float4 v = s[off];
    ushort4 o; o.x = f2bf(v.x); o.y = f2bf(v.y); o.z = f2bf(v.z); o.w = f2bf(v.w);
    *(ushort4*)(Wb + ((size_t)w << 20) + (size_t)off * 4) = o;
  }
}

// ---------------------------------------------------------------------------
// Fused QKV GEMM, 256x256 tile, BK=64, 512 thr / 8 waves (2Mx4N), dbuf.
// Per K-tile: {stage ALL of kt+1 (8 gl_lds); vmcnt(8); s_barrier;
//              24 ds_read + 64 MFMA (compiler-scheduled, no barriers);
//              s_barrier}. Counted vmcnt: tile kt's loads had a FULL K-tile
// in flight; the just-issued 8 stay outstanding across the wait.
// Race ledger: buf bx (= tile kt-1's buffer) last read before kt-1's END
// barrier; kt's staging issues after it. vmcnt(8)+barrier at kt's top ensure
// every wave's tile-kt loads landed before any wave's ds_read of tile kt.
__global__ __launch_bounds__(512, 2) void gemm_qkv(const u16* __restrict__ Hb, const u16* __restrict__ Ib,
                                                   const u16* __restrict__ Wb,
                                                   u16* __restrict__ Qd, u16* __restrict__ Kd,
                                                   u16* __restrict__ Vd)
{
  __shared__ __align__(16) u16 As[2 * 16384];   // 64 KB
  __shared__ __align__(16) u16 Bs[2 * 16384];   // 64 KB
  const int bid = blockIdx.x;
  const u16 *A, *Bm;
  int bm, bn, mode;
  if (bid < 192) { mode = 4; A = Hb; Bm = Wb;
                   bm = (bid / 12) * 256; bn = (bid % 12) * 256; }
  else           { mode = 5; A = Ib; Bm = Wb + 3 * 1048576;
                   int r = bid - 192; bm = (r >> 3) * 256; bn = (r & 7) * 256; }
  const int tid = threadIdx.x, lane = tid & 63, wave = tid >> 6;
  const int wr = wave >> 2, wc = wave & 3;      // 2M x 4N
  const int g = lane >> 4, c = lane & 15, cs = c & 7;
  const int srow = tid >> 3;                    // 0..63
  const int pch  = tid & 7;
  const int swz  = (pch ^ (srow & 7)) * 8;      // XOR-chunk swizzle (involution)

  f32x4 zf = {0.f, 0.f, 0.f, 0.f};
  f32x4 acc[8][4];
  #pragma unroll
  for (int f = 0; f < 8; ++f)
    #pragma unroll
    for (int nf = 0; nf < 4; ++nf) acc[f][nf] = zf;

  // stage a FULL K-tile (A: 256x64 + B: 256x64) = 4+4 gl_lds per thread
  #define STG_ALL(buf, kt)                                                          \
    do {                                                                            \
      _Pragma("unroll")                                                             \
      for (int j_ = 0; j_ < 4; ++j_) {                                              \
        int row_ = j_ * 64 + srow;                                                  \
        gl_lds16(A + (size_t)(bm + row_) * 1024 + (kt) * 64 + swz,                  \
                 &As[(buf) + row_ * 64 + pch * 8]);                                 \
      }                                                                             \
      _Pragma("unroll")                                                             \
      for (int j_ = 0; j_ < 4; ++j_) {                                              \
        int row_ = j_ * 64 + srow;                                                  \
        gl_lds16(Bm + (size_t)(bn + row_) * 1024 + (kt) * 64 + swz,                 \
                 &Bs[(buf) + row_ * 64 + pch * 8]);                                 \
      }                                                                             \
    } while (0)

  STG_ALL(0, 0);   // prologue: tile 0 into buffer 0

  for (int kt = 0; kt < 16; ++kt) {
    const int bc = (kt & 1) * 16384;
    const int bx = bc ^ 16384;
    if (kt < 15) {
      STG_ALL(bx, kt + 1);
      asm volatile("s_waitcnt vmcnt(8)" ::: "memory");   // drain tile kt only
    } else {
      asm volatile("s_waitcnt vmcnt(0)" ::: "memory");
    }
    asm volatile("s_barrier" ::: "memory");

    // B-frags for the whole K-tile (8 ds_read_b128)
    bf16x8v Bf[4][2];
    #pragma unroll
    for (int nf = 0; nf < 4; ++nf)
      #pragma unroll
      for (int ks = 0; ks < 2; ++ks)
        Bf[nf][ks] = *(const bf16x8v*)&Bs[bc + (wc * 64 + nf * 16 + c) * 64 + ((ks * 4 + g) ^ cs) * 8];

    #pragma unroll
    for (int p = 0; p < 4; ++p) {
      bf16x8v Af[2][2];
      #pragma unroll
      for (int i = 0; i < 2; ++i)
        #pragma unroll
        for (int ks = 0; ks < 2; ++ks)
          Af[i][ks] = *(const bf16x8v*)&As[bc + (wr * 128 + (p * 2 + i) * 16 + c) * 64 + ((ks * 4 + g) ^ cs) * 8];
      __builtin_amdgcn_s_setprio(1);
      #pragma unroll
      for (int i = 0; i < 2; ++i)
        #pragma unroll
        for (int nf = 0; nf < 4; ++nf)
          #pragma unroll
          for (int ks = 0; ks < 2; ++ks)
            acc[p * 2 + i][nf] =
              __builtin_amdgcn_mfma_f32_16x16x32_bf16(Af[i][ks], Bf[nf][ks], acc[p * 2 + i][nf], 0, 0, 0);
      __builtin_amdgcn_s_setprio(0);
    }
    asm volatile("s_barrier" ::: "memory");   // all waves done reading bc
  }
  #undef STG_ALL

  // epilogue: C row = 4*g + j, col = c (verified R7)
  #pragma unroll
  for (int f = 0; f < 8; ++f) {
    #pragma unroll
    for (int nf = 0; nf < 4; ++nf) {
      #pragma unroll
      for (int j = 0; j < 4; ++j) {
        int gm = bm + wr * 128 + f * 16 + 4 * g + j;
        int gn = bn + wc * 64 + nf * 16 + c;
        float v = acc[f][nf][j];
        if (mode == 4) {
          int b_ = gm >> 10, s_ = gm & 1023;
          if (gn < 1024)      Qd[(size_t)gm * 1024 + gn] = f2bf(v * 0.18033688011112042f);
          else if (gn < 2048) Kd[(size_t)(b_ * 1536 + s_) * 1024 + (gn - 1024)] = f2bf(v);
          else                Vd[(size_t)(b_ * 1024 + (gn - 2048)) * 1536 + s_] = f2bf(v);
        } else {
          int b_ = gm >> 9, s_ = gm & 511;
          if (gn < 1024) Kd[(size_t)(b_ * 1536 + 1024 + s_) * 1024 + gn] = f2bf(v);
          else           Vd[(size_t)(b_ * 1024 + (gn - 1024)) * 1536 + 1024 + s_] = f2bf(v);
        }
      }
    }
  }
}

// ---------------------------------------------------------------------------
// out-proj GEMM: 128x128 tile, BK=64, 256 thr / 4 waves (2x2), same
// full-slack dbuf schedule (64 KB LDS -> 2 blocks/CU). fp32 out.
__global__ __launch_bounds__(256) void gemm_out(const u16* __restrict__ A, const u16* __restrict__ Bm,
                                                float* __restrict__ Cout)
{
  __shared__ __align__(16) u16 As[2 * 8192];   // 32 KB
  __shared__ __align__(16) u16 Bs[2 * 8192];   // 32 KB
  const int tid  = threadIdx.x;
  const int lane = tid & 63, wave = tid >> 6;
  const int wr = wave >> 1, wc = wave & 1;
  const int g = lane >> 4, c = lane & 15, cs = c & 7;
  const int bm = blockIdx.y * 128;
  const int bn = blockIdx.x * 128;
  const int sr  = tid >> 3;          // 0..31
  const int pch = tid & 7;
  const int swz = (pch ^ (sr & 7)) * 8;

  f32x4 zf = {0.f, 0.f, 0.f, 0.f};
  f32x4 acc[4][4];
  #pragma unroll
  for (int mi = 0; mi < 4; ++mi)
    #pragma unroll
    for (int ni = 0; ni < 4; ++ni) acc[mi][ni] = zf;

  #define STGO(buf, kt)                                                             \
    do {                                                                            \
      _Pragma("unroll")                                                             \
      for (int q_ = 0; q_ < 4; ++q_) {                                              \
        int row_ = q_ * 32 + sr;                                                    \
        gl_lds16(A + (size_t)(bm + row_) * 1024 + (kt) * 64 + swz,                  \
                 &As[(buf) + row_ * 64 + pch * 8]);                                 \
      }                                                                             \
      _Pragma("unroll")                                                             \
      for (int q_ = 0; q_ < 4; ++q_) {                                              \
        int row_ = q_ * 32 + sr;                                                    \
        gl_lds16(Bm + (size_t)(bn + row_) * 1024 + (kt) * 64 + swz,                 \
                 &Bs[(buf) + row_ * 64 + pch * 8]);                                 \
      }                                                                             \
    } while (0)

  STGO(0, 0);

  for (int kt = 0; kt < 16; ++kt) {
    const int bc = (kt & 1) * 8192;
    const int bx = bc ^ 8192;
    if (kt < 15) {
      STGO(bx, kt + 1);
      asm volatile("s_waitcnt vmcnt(8)" ::: "memory");
    } else {
      asm volatile("s_waitcnt vmcnt(0)" ::: "memory");
    }
    asm volatile("s_barrier" ::: "memory");

    #pragma unroll
    for (int ks = 0; ks < 2; ++ks) {
      bf16x8v af[4], bfr[4];
      #pragma unroll
      for (int mi = 0; mi < 4; ++mi)
        af[mi] = *(const bf16x8v*)&As[bc + (wr * 64 + mi * 16 + c) * 64 + ((ks * 4 + g) ^ cs) * 8];
      #pragma unroll
      for (int ni = 0; ni < 4; ++ni)
        bfr[ni] = *(const bf16x8v*)&Bs[bc + (wc * 64 + ni * 16 + c) * 64 + ((ks * 4 + g) ^ cs) * 8];
      __builtin_amdgcn_s_setprio(1);
      #pragma unroll
      for (int mi = 0; mi < 4; ++mi)
        #pragma unroll
        for (int ni = 0; ni < 4; ++ni)
          acc[mi][ni] = __builtin_amdgcn_mfma_f32_16x16x32_bf16(af[mi], bfr[ni], acc[mi][ni], 0, 0, 0);
      __builtin_amdgcn_s_setprio(0);
    }
    asm volatile("s_barrier" ::: "memory");
  }
  #undef STGO

  #pragma unroll
  for (int mi = 0; mi < 4; ++mi)
    #pragma unroll
    for (int ni = 0; ni < 4; ++ni)
      #pragma unroll
      for (int j = 0; j < 4; ++j) {
        int gm = bm + wr * 64 + mi * 16 + 4 * g + j;
        int gn = bn + wc * 64 + ni * 16 + c;
        Cout[(size_t)gm * 1024 + gn] = acc[mi][ni][j];
      }
}

// ---------------------------------------------------------------------------
// flash attention, swapped QK^T, max-free softmax (round-4 known-good)
__global__ __launch_bounds__(256) void attn_kernel(const u16* __restrict__ Q, const u16* __restrict__ Kc,
                                                   const u16* __restrict__ Vt,
                                                   const uint32_t* __restrict__ Mw,
                                                   u16* __restrict__ AO)
{
  const int bid = blockIdx.x;
  const int grp = bid & 63;           // (b,h) group; XCD = bid%8 = grp%8
  const int qt  = bid >> 6;
  const int h = grp & 15, b = grp >> 4;
  const int q0 = qt * 64;
  const int tid = threadIdx.x, lane = tid & 63, wave = tid >> 6;
  const int g = lane >> 4, c = lane & 15;
  const int qw = q0 + wave * 16;

  __shared__ __align__(16) u16 Ks[64 * 64];      // 8 KB
  __shared__ __align__(16) u16 Vs[64 * 64];      // 8 KB  [d][l]
  __shared__ __align__(16) u16 Ps[4][16 * 72];   // 9 KB  per-wave P, padded

  bf16x8v qf0, qf1;
  {
    const u16* qp = Q + (size_t)(b * 1024 + qw + c) * 1024 + h * 64 + g * 8;
    qf0 = *(const bf16x8v*)qp;
    qf1 = *(const bf16x8v*)(qp + 32);
  }
  f32x4 zf = {0.f, 0.f, 0.f, 0.f};
  f32x4 O[4];                       // O^T frag: [d=dt*16+4g+j][q=c]
  float l = 0.f;                    // per-lane partial denominator
  #pragma unroll
  for (int dt = 0; dt < 4; ++dt) O[dt] = zf;

  const int sr  = tid >> 3;         // 0..31
  const int pch = tid & 7;
  const int swz = (pch ^ (sr & 7)) * 8;   // write-side XOR swizzle
  const int cs  = c & 7;
  const u16* Kbase = Kc + (size_t)(b * 1536) * 1024 + h * 64;
  const u16* Vbase = Vt + (size_t)(b * 1024 + h * 64) * 1536;
  const uint32_t* mrow = Mw + (size_t)(b * 1024 + qw + c) * 48;

  bf16x8v kr0, kr1, vr0, vr1;
  kr0 = *(const bf16x8v*)(Kbase + (size_t)sr * 1024 + pch * 8);
  kr1 = *(const bf16x8v*)(Kbase + (size_t)(32 + sr) * 1024 + pch * 8);
  vr0 = *(const bf16x8v*)(Vbase + (size_t)sr * 1536 + pch * 8);
  vr1 = *(const bf16x8v*)(Vbase + (size_t)(32 + sr) * 1536 + pch * 8);
  *(bf16x8v*)&Ks[sr * 64 + swz]        = kr0;
  *(bf16x8v*)&Ks[(32 + sr) * 64 + swz] = kr1;
  *(bf16x8v*)&Vs[sr * 64 + swz]        = vr0;
  *(bf16x8v*)&Vs[(32 + sr) * 64 + swz] = vr1;
  __syncthreads();

  for (int kt = 0; kt < 24; ++kt) {
    if (kt < 23) {
      const int ln = (kt + 1) * 64;
      kr0 = *(const bf16x8v*)(Kbase + (size_t)(ln + sr) * 1024 + pch * 8);
      kr1 = *(const bf16x8v*)(Kbase + (size_t)(ln + 32 + sr) * 1024 + pch * 8);
      vr0 = *(const bf16x8v*)(Vbase + (size_t)sr * 1536 + ln + pch * 8);
      vr1 = *(const bf16x8v*)(Vbase + (size_t)(32 + sr) * 1536 + ln + pch * 8);
    }
    uint2 mwv = *(const uint2*)(mrow + kt * 2);

    f32x4 s[4];
    __builtin_amdgcn_s_setprio(1);
    #pragma unroll
    for (int nt = 0; nt < 4; ++nt) {
      const u16* kr = &Ks[(nt * 16 + c) * 64];
      bf16x8v k0 = *(const bf16x8v*)&kr[(g ^ cs) * 8];
      bf16x8v k1 = *(const bf16x8v*)&kr[((4 + g) ^ cs) * 8];
      f32x4 z = zf;
      z = __builtin_amdgcn_mfma_f32_16x16x32_bf16(k0, qf0, z, 0, 0, 0);
      z = __builtin_amdgcn_mfma_f32_16x16x32_bf16(k1, qf1, z, 0, 0, 0);
      s[nt] = z;
    }
    __builtin_amdgcn_s_setprio(0);

    uint64_t mq = (((uint64_t)mwv.y << 32) | (uint64_t)mwv.x) >> (4 * g);
    uint32_t mlo = (uint32_t)mq, mhi = (uint32_t)(mq >> 32);
    #pragma unroll
    for (int nt = 0; nt < 4; ++nt) {
      uint32_t msrc = (nt < 2) ? mlo : mhi;
      #pragma unroll
      for (int j = 0; j < 4; ++j) {
        float e = exp2f(s[nt][j]);
        float p = maskand(e, msrc, 16 * (nt & 1) + j);
        s[nt][j] = p;
        l += p;
      }
    }

    u16* pw = &Ps[wave][0];
    #pragma unroll
    for (int nt = 0; nt < 4; ++nt) {
      uint2 pk2;
      pk2.x = cvtpk(s[nt][0], s[nt][1]);
      pk2.y = cvtpk(s[nt][2], s[nt][3]);
      *(uint2*)&pw[c * 72 + nt * 16 + g * 4] = pk2;
    }
    bf16x8v pb0 = *(const bf16x8v*)&pw[c * 72 + g * 8];
    bf16x8v pb1 = *(const bf16x8v*)&pw[c * 72 + 32 + g * 8];
    __builtin_amdgcn_s_setprio(1);
    #pragma unroll
    for (int dt = 0; dt < 4; ++dt) {
      const u16* vr = &Vs[(dt * 16 + c) * 64];
      bf16x8v v0 = *(const bf16x8v*)&vr[(g ^ cs) * 8];
      bf16x8v v1 = *(const bf16x8v*)&vr[((4 + g) ^ cs) * 8];
      O[dt] = __builtin_amdgcn_mfma_f32_16x16x32_bf16(v0, pb0, O[dt], 0, 0, 0);
      O[dt] = __builtin_amdgcn_mfma_f32_16x16x32_bf16(v1, pb1, O[dt], 0, 0, 0);
    }
    __builtin_amdgcn_s_setprio(0);

    __syncthreads();                 // all waves done READING Ks/Vs
    if (kt < 23) {
      *(bf16x8v*)&Ks[sr * 64 + swz]        = kr0;
      *(bf16x8v*)&Ks[(32 + sr) * 64 + swz] = kr1;
      *(bf16x8v*)&Vs[sr * 64 + swz]        = vr0;
      *(bf16x8v*)&Vs[(32 + sr) * 64 + swz] = vr1;
      __syncthreads();
    }
  }

  float r = l;
  r += __shfl_xor(r, 16);
  r += __shfl_xor(r, 32);
  float inv = 1.f / r;
  size_t ro = (size_t)(b * 1024 + qw + c) * 1024 + h * 64;
  #pragma unroll
  for (int dt = 0; dt < 4; ++dt) {
    uint2 st;
    st.x = cvtpk(O[dt][0] * inv, O[dt][1] * inv);
    st.y = cvtpk(O[dt][2] * inv, O[dt][3] * inv);
    *(uint2*)&AO[ro + dt * 16 + 4 * g] = st;
  }
}

// ---------------------------------------------------------------------------
extern "C" void kernel_launch(void* const* d_in, const int* in_sizes, int n_in,
                              void* d_out, int out_size, void* d_ws, size_t ws_size,
                              hipStream_t stream) {
  (void)in_sizes; (void)n_in; (void)out_size; (void)ws_size;
  const float* hs = (const float*)d_in[0];
  const float* im = (const float*)d_in[1];
  const int*   mk = (const int*)d_in[2];
  const float* wq = (const float*)d_in[3];
  const float* wk = (const float*)d_in[4];
  const float* wv = (const float*)d_in[5];
  const float* uk = (const float*)d_in[6];
  const float* uv = (const float*)d_in[7];
  const float* wo = (const float*)d_in[8];

  char* ws = (char*)d_ws;
  u16* Hb  = (u16*)(ws + 0);          //  8,388,608 B  hidden bf16; reused as attn-out
  u16* Ib  = (u16*)(ws + 8388608);    //  4,194,304 B  image bf16
  u16* Wb  = (u16*)(ws + 12582912);   // 12,582,912 B  weights bf16 (wq wk wv uk uv wo)
  u16* Qb  = (u16*)(ws + 25165824);   //  8,388,608 B  Q token-major [4096][1024] (pre-scaled)
  u16* Kb  = (u16*)(ws + 33554432);   // 12,582,912 B  K concat [4][1536][1024]
  u16* Vtb = (u16*)(ws + 46137344);   // 12,582,912 B  V transposed [4][1024][1536]
  uint32_t* Mw = (uint32_t*)(ws + 58720256); // 786,432 B packed mask
  // total ws: 59,506,688 B

  prep<<<2048, 256, 0, stream>>>(mk, (const float4*)hs, (const float4*)im,
                                 (const float4*)wq, (const float4*)wk, (const float4*)wv,
                                 (const float4*)uk, (const float4*)uv, (const float4*)wo,
                                 Mw, Hb, Ib, Wb);
  gemm_qkv<<<256, 512, 0, stream>>>(Hb, Ib, Wb, Qb, Kb, Vtb);
  attn_kernel<<<1024, 256, 0, stream>>>(Qb, Kb, Vtb, Mw, Hb);
  gemm_out<<<dim3(8, 32), 256, 0, stream>>>(Hb, Wb + 5 * 1048576, (float*)d_out);
}

// Round 9
// 159.981 us; speedup vs baseline: 1.0848x; 1.0337x over previous
//
#include <hip/hip_runtime.h>
#include <stdint.h>

// ---------------------------------------------------------------------------
// CustomGPT2MultiHeadAttention: B=4, S=1024, SI=512, D=1024, H=16, Dh=64
// Round 9: GEMMs = exact T3-minimum 2-phase (stage-next FIRST, compute current,
// ONE vmcnt(0)+s_barrier per K-tile) + T1 XCD-affine block remap (each XCD
// owns whole A-row-groups -> A-panel L2-resident). attn/prep = round-4.
// ---------------------------------------------------------------------------

typedef unsigned short u16;
typedef short bf16x8v __attribute__((ext_vector_type(8)));
typedef float f32x4 __attribute__((ext_vector_type(4)));

__device__ __forceinline__ u16 f2bf(float f) {
  union { float f; uint32_t u; } x; x.f = f;
  uint32_t r = x.u + 0x7FFFu + ((x.u >> 16) & 1u);   // round-to-nearest-even
  return (u16)(r >> 16);
}

// v_cvt_pk_bf16_f32: D[15:0]=bf16(a), D[31:16]=bf16(b), RNE
__device__ __forceinline__ uint32_t cvtpk(float a, float b) {
  uint32_t r;
  asm("v_cvt_pk_bf16_f32 %0, %1, %2" : "=v"(r) : "v"(a), "v"(b));
  return r;
}

// p = bit(msrc,off) ? e : 0   via sign-extended 1-bit field + AND (2 VALU)
__device__ __forceinline__ float maskand(float e, uint32_t msrc, int off) {
  uint32_t mm = (uint32_t)((int32_t)(msrc << (31 - off)) >> 31);
  union { float f; uint32_t u; } x; x.f = e; x.u &= mm; return x.f;
}

__device__ __forceinline__ void gl_lds16(const u16* g, u16* l) {
  __builtin_amdgcn_global_load_lds((const __attribute__((address_space(1))) unsigned int*)g,
                                   (__attribute__((address_space(3))) unsigned int*)l,
                                   16, 0, 0);
}

// ---------------------------------------------------------------------------
// 1) fused prep: mask bit-pack + hidden/image cast + 6-weight cast.
__global__ __launch_bounds__(256) void prep(const int* __restrict__ mk,
                                            const float4* __restrict__ hs,
                                            const float4* __restrict__ im,
                                            const float4* __restrict__ w0, const float4* __restrict__ w1,
                                            const float4* __restrict__ w2, const float4* __restrict__ w3,
                                            const float4* __restrict__ w4, const float4* __restrict__ w5,
                                            uint32_t* __restrict__ Mw,
                                            u16* __restrict__ Hb, u16* __restrict__ Ib,
                                            u16* __restrict__ Wb) {
  const int nthr = gridDim.x * 256;
  const int gid = blockIdx.x * 256 + threadIdx.x;

  for (int w = gid; w < 196608; w += nthr) {
    const int4* p = (const int4*)(mk + (size_t)w * 32);
    uint32_t bits = 0;
    #pragma unroll
    for (int c = 0; c < 8; ++c) {
      int4 v = p[c];
      bits |= (uint32_t)(v.x != 0) << (4 * c);
      bits |= (uint32_t)(v.y != 0) << (4 * c + 1);
      bits |= (uint32_t)(v.z != 0) << (4 * c + 2);
      bits |= (uint32_t)(v.w != 0) << (4 * c + 3);
    }
    Mw[w] = bits;
  }
  for (int i = gid; i < 1572864; i += nthr) {
    float4 v; u16* d;
    if (i < 1048576) { v = hs[i];            d = Hb + (size_t)i * 4; }
    else             { v = im[i - 1048576];  d = Ib + (size_t)(i - 1048576) * 4; }
    ushort4 o; o.x = f2bf(v.x); o.y = f2bf(v.y); o.z = f2bf(v.z); o.w = f2bf(v.w);
    *(ushort4*)d = o;
  }
  for (int i = gid; i < 1572864; i += nthr) {
    int w = i >> 18, off = i & 262143;
    const float4* s;
    switch (w) {
      case 0: s = w0; break; case 1: s = w1; break; case 2: s = w2; break;
      case 3: s = w3; break; case 4: s = w4; break; default: s = w5; break;
    }
    float4 v = s[off];
    ushort4 o; o.x = f2bf(v.x); o.y = f2bf(v.y); o.z = f2bf(v.z); o.w = f2bf(v.w);
    *(ushort4*)(Wb + ((size_t)w << 20) + (size_t)off * 4) = o;
  }
}

// ---------------------------------------------------------------------------
// Fused QKV GEMM, 256x256 tile, BK=64, 512 thr / 8 waves (2Mx4N), dbuf.
// T3-minimum 2-phase, single barrier per K-tile:
//   prologue: STAGE(buf0,0); vmcnt(0); barrier;
//   for t:    STAGE(buf^1, t+1)      [issued FIRST — flies under MFMA]
//             ds_read cur + 64 MFMA  [compiler-managed lgkmcnt ordering]
//             vmcnt(0); s_barrier    [loads had the whole MFMA phase]
// T1 XCD-affine remap: XCD x owns self row-groups {2x,2x+1} (A-panels
// L2-resident, reused 12x) + image row-group x (reused 8x).
__global__ __launch_bounds__(512, 2) void gemm_qkv(const u16* __restrict__ Hb, const u16* __restrict__ Ib,
                                                   const u16* __restrict__ Wb,
                                                   u16* __restrict__ Qd, u16* __restrict__ Kd,
                                                   u16* __restrict__ Vd)
{
  __shared__ __align__(16) u16 As[2 * 16384];   // 64 KB
  __shared__ __align__(16) u16 Bs[2 * 16384];   // 64 KB
  // XCD-affine remap: hardware bid -> XCD = hb%8; slot = hb/8 (0..31)
  const int hb = blockIdx.x;
  const int xcd = hb & 7, slot = hb >> 3;
  int bid;                                      // logical tile id
  if (slot < 24) bid = xcd * 24 + slot;         // self: 0..191  (rg = bid/12)
  else           bid = 192 + xcd * 8 + (slot - 24);  // image: 192..255
  const u16 *A, *Bm;
  int bm, bn, mode;
  if (bid < 192) { mode = 4; A = Hb; Bm = Wb;
                   bm = (bid / 12) * 256; bn = (bid % 12) * 256; }
  else           { mode = 5; A = Ib; Bm = Wb + 3 * 1048576;
                   int r = bid - 192; bm = (r >> 3) * 256; bn = (r & 7) * 256; }
  const int tid = threadIdx.x, lane = tid & 63, wave = tid >> 6;
  const int wr = wave >> 2, wc = wave & 3;      // 2M x 4N
  const int g = lane >> 4, c = lane & 15, cs = c & 7;
  const int srow = tid >> 3;                    // 0..63
  const int pch  = tid & 7;
  const int swz  = (pch ^ (srow & 7)) * 8;      // XOR-chunk swizzle (involution)

  f32x4 zf = {0.f, 0.f, 0.f, 0.f};
  f32x4 acc[8][4];
  #pragma unroll
  for (int f = 0; f < 8; ++f)
    #pragma unroll
    for (int nf = 0; nf < 4; ++nf) acc[f][nf] = zf;

  // stage a FULL K-tile (A: 256x64 + B: 256x64) = 4+4 gl_lds per thread
  #define STG_ALL(buf, kt)                                                          \
    do {                                                                            \
      _Pragma("unroll")                                                             \
      for (int j_ = 0; j_ < 4; ++j_) {                                              \
        int row_ = j_ * 64 + srow;                                                  \
        gl_lds16(A + (size_t)(bm + row_) * 1024 + (kt) * 64 + swz,                  \
                 &As[(buf) + row_ * 64 + pch * 8]);                                 \
      }                                                                             \
      _Pragma("unroll")                                                             \
      for (int j_ = 0; j_ < 4; ++j_) {                                              \
        int row_ = j_ * 64 + srow;                                                  \
        gl_lds16(Bm + (size_t)(bn + row_) * 1024 + (kt) * 64 + swz,                 \
                 &Bs[(buf) + row_ * 64 + pch * 8]);                                 \
      }                                                                             \
    } while (0)

  // prologue: tile 0 resident before the loop
  STG_ALL(0, 0);
  asm volatile("s_waitcnt vmcnt(0)" ::: "memory");
  asm volatile("s_barrier" ::: "memory");

  for (int kt = 0; kt < 16; ++kt) {
    const int bc = (kt & 1) * 16384;
    const int bx = bc ^ 16384;
    if (kt < 15) STG_ALL(bx, kt + 1);           // issue next-tile loads FIRST

    // compute current tile (resident); compiler orders ds_read -> MFMA
    bf16x8v Bf[4][2];
    #pragma unroll
    for (int nf = 0; nf < 4; ++nf)
      #pragma unroll
      for (int ks = 0; ks < 2; ++ks)
        Bf[nf][ks] = *(const bf16x8v*)&Bs[bc + (wc * 64 + nf * 16 + c) * 64 + ((ks * 4 + g) ^ cs) * 8];

    #pragma unroll
    for (int p = 0; p < 4; ++p) {
      bf16x8v Af[2][2];
      #pragma unroll
      for (int i = 0; i < 2; ++i)
        #pragma unroll
        for (int ks = 0; ks < 2; ++ks)
          Af[i][ks] = *(const bf16x8v*)&As[bc + (wr * 128 + (p * 2 + i) * 16 + c) * 64 + ((ks * 4 + g) ^ cs) * 8];
      __builtin_amdgcn_s_setprio(1);
      #pragma unroll
      for (int i = 0; i < 2; ++i)
        #pragma unroll
        for (int nf = 0; nf < 4; ++nf)
          #pragma unroll
          for (int ks = 0; ks < 2; ++ks)
            acc[p * 2 + i][nf] =
              __builtin_amdgcn_mfma_f32_16x16x32_bf16(Af[i][ks], Bf[nf][ks], acc[p * 2 + i][nf], 0, 0, 0);
      __builtin_amdgcn_s_setprio(0);
    }

    if (kt < 15) {
      asm volatile("s_waitcnt vmcnt(0)" ::: "memory");  // next tile landed (flew under MFMA)
      asm volatile("s_barrier" ::: "memory");            // reads of bc done; bx visible to all
    }
  }
  #undef STG_ALL

  // epilogue: C row = 4*g + j, col = c (verified R7)
  #pragma unroll
  for (int f = 0; f < 8; ++f) {
    #pragma unroll
    for (int nf = 0; nf < 4; ++nf) {
      #pragma unroll
      for (int j = 0; j < 4; ++j) {
        int gm = bm + wr * 128 + f * 16 + 4 * g + j;
        int gn = bn + wc * 64 + nf * 16 + c;
        float v = acc[f][nf][j];
        if (mode == 4) {
          int b_ = gm >> 10, s_ = gm & 1023;
          if (gn < 1024)      Qd[(size_t)gm * 1024 + gn] = f2bf(v * 0.18033688011112042f);
          else if (gn < 2048) Kd[(size_t)(b_ * 1536 + s_) * 1024 + (gn - 1024)] = f2bf(v);
          else                Vd[(size_t)(b_ * 1024 + (gn - 2048)) * 1536 + s_] = f2bf(v);
        } else {
          int b_ = gm >> 9, s_ = gm & 511;
          if (gn < 1024) Kd[(size_t)(b_ * 1536 + 1024 + s_) * 1024 + gn] = f2bf(v);
          else           Vd[(size_t)(b_ * 1024 + (gn - 1024)) * 1536 + 1024 + s_] = f2bf(v);
        }
      }
    }
  }
}

// ---------------------------------------------------------------------------
// out-proj GEMM: 128x128 tile, BK=64, 256 thr / 4 waves (2x2), T3-minimum
// 2-phase single-barrier, XCD-affine remap (XCD x: 4 row-groups x 8 cols).
// M=4096 N=1024 K=1024, fp32 out. 1D grid of 256.
__global__ __launch_bounds__(256) void gemm_out(const u16* __restrict__ A, const u16* __restrict__ Bm,
                                                float* __restrict__ Cout)
{
  __shared__ __align__(16) u16 As[2 * 8192];   // 32 KB
  __shared__ __align__(16) u16 Bs[2 * 8192];   // 32 KB
  const int hb = blockIdx.x;
  const int xcd = hb & 7, slot = hb >> 3;      // slot 0..31
  const int rg = xcd * 4 + (slot >> 3);        // 0..31
  const int cg = slot & 7;                     // 0..7
  const int bm = rg * 128, bn = cg * 128;
  const int tid  = threadIdx.x;
  const int lane = tid & 63, wave = tid >> 6;
  const int wr = wave >> 1, wc = wave & 1;
  const int g = lane >> 4, c = lane & 15, cs = c & 7;
  const int sr  = tid >> 3;          // 0..31
  const int pch = tid & 7;
  const int swz = (pch ^ (sr & 7)) * 8;

  f32x4 zf = {0.f, 0.f, 0.f, 0.f};
  f32x4 acc[4][4];
  #pragma unroll
  for (int mi = 0; mi < 4; ++mi)
    #pragma unroll
    for (int ni = 0; ni < 4; ++ni) acc[mi][ni] = zf;

  #define STGO(buf, kt)                                                             \
    do {                                                                            \
      _Pragma("unroll")                                                             \
      for (int q_ = 0; q_ < 4; ++q_) {                                              \
        int row_ = q_ * 32 + sr;                                                    \
        gl_lds16(A + (size_t)(bm + row_) * 1024 + (kt) * 64 + swz,                  \
                 &As[(buf) + row_ * 64 + pch * 8]);                                 \
      }                                                                             \
      _Pragma("unroll")                                                             \
      for (int q_ = 0; q_ < 4; ++q_) {                                              \
        int row_ = q_ * 32 + sr;                                                    \
        gl_lds16(Bm + (size_t)(bn + row_) * 1024 + (kt) * 64 + swz,                 \
                 &Bs[(buf) + row_ * 64 + pch * 8]);                                 \
      }                                                                             \
    } while (0)

  STGO(0, 0);
  asm volatile("s_waitcnt vmcnt(0)" ::: "memory");
  asm volatile("s_barrier" ::: "memory");

  for (int kt = 0; kt < 16; ++kt) {
    const int bc = (kt & 1) * 8192;
    const int bx = bc ^ 8192;
    if (kt < 15) STGO(bx, kt + 1);

    #pragma unroll
    for (int ks = 0; ks < 2; ++ks) {
      bf16x8v af[4], bfr[4];
      #pragma unroll
      for (int mi = 0; mi < 4; ++mi)
        af[mi] = *(const bf16x8v*)&As[bc + (wr * 64 + mi * 16 + c) * 64 + ((ks * 4 + g) ^ cs) * 8];
      #pragma unroll
      for (int ni = 0; ni < 4; ++ni)
        bfr[ni] = *(const bf16x8v*)&Bs[bc + (wc * 64 + ni * 16 + c) * 64 + ((ks * 4 + g) ^ cs) * 8];
      __builtin_amdgcn_s_setprio(1);
      #pragma unroll
      for (int mi = 0; mi < 4; ++mi)
        #pragma unroll
        for (int ni = 0; ni < 4; ++ni)
          acc[mi][ni] = __builtin_amdgcn_mfma_f32_16x16x32_bf16(af[mi], bfr[ni], acc[mi][ni], 0, 0, 0);
      __builtin_amdgcn_s_setprio(0);
    }

    if (kt < 15) {
      asm volatile("s_waitcnt vmcnt(0)" ::: "memory");
      asm volatile("s_barrier" ::: "memory");
    }
  }
  #undef STGO

  #pragma unroll
  for (int mi = 0; mi < 4; ++mi)
    #pragma unroll
    for (int ni = 0; ni < 4; ++ni)
      #pragma unroll
      for (int j = 0; j < 4; ++j) {
        int gm = bm + wr * 64 + mi * 16 + 4 * g + j;
        int gn = bn + wc * 64 + ni * 16 + c;
        Cout[(size_t)gm * 1024 + gn] = acc[mi][ni][j];
      }
}

// ---------------------------------------------------------------------------
// flash attention, swapped QK^T, max-free softmax (round-4 known-good)
__global__ __launch_bounds__(256) void attn_kernel(const u16* __restrict__ Q, const u16* __restrict__ Kc,
                                                   const u16* __restrict__ Vt,
                                                   const uint32_t* __restrict__ Mw,
                                                   u16* __restrict__ AO)
{
  const int bid = blockIdx.x;
  const int grp = bid & 63;           // (b,h) group; XCD = bid%8 = grp%8
  const int qt  = bid >> 6;
  const int h = grp & 15, b = grp >> 4;
  const int q0 = qt * 64;
  const int tid = threadIdx.x, lane = tid & 63, wave = tid >> 6;
  const int g = lane >> 4, c = lane & 15;
  const int qw = q0 + wave * 16;

  __shared__ __align__(16) u16 Ks[64 * 64];      // 8 KB
  __shared__ __align__(16) u16 Vs[64 * 64];      // 8 KB  [d][l]
  __shared__ __align__(16) u16 Ps[4][16 * 72];   // 9 KB  per-wave P, padded

  bf16x8v qf0, qf1;
  {
    const u16* qp = Q + (size_t)(b * 1024 + qw + c) * 1024 + h * 64 + g * 8;
    qf0 = *(const bf16x8v*)qp;
    qf1 = *(const bf16x8v*)(qp + 32);
  }
  f32x4 zf = {0.f, 0.f, 0.f, 0.f};
  f32x4 O[4];                       // O^T frag: [d=dt*16+4g+j][q=c]
  float l = 0.f;                    // per-lane partial denominator
  #pragma unroll
  for (int dt = 0; dt < 4; ++dt) O[dt] = zf;

  const int sr  = tid >> 3;         // 0..31
  const int pch = tid & 7;
  const int swz = (pch ^ (sr & 7)) * 8;   // write-side XOR swizzle
  const int cs  = c & 7;
  const u16* Kbase = Kc + (size_t)(b * 1536) * 1024 + h * 64;
  const u16* Vbase = Vt + (size_t)(b * 1024 + h * 64) * 1536;
  const uint32_t* mrow = Mw + (size_t)(b * 1024 + qw + c) * 48;

  bf16x8v kr0, kr1, vr0, vr1;
  kr0 = *(const bf16x8v*)(Kbase + (size_t)sr * 1024 + pch * 8);
  kr1 = *(const bf16x8v*)(Kbase + (size_t)(32 + sr) * 1024 + pch * 8);
  vr0 = *(const bf16x8v*)(Vbase + (size_t)sr * 1536 + pch * 8);
  vr1 = *(const bf16x8v*)(Vbase + (size_t)(32 + sr) * 1536 + pch * 8);
  *(bf16x8v*)&Ks[sr * 64 + swz]        = kr0;
  *(bf16x8v*)&Ks[(32 + sr) * 64 + swz] = kr1;
  *(bf16x8v*)&Vs[sr * 64 + swz]        = vr0;
  *(bf16x8v*)&Vs[(32 + sr) * 64 + swz] = vr1;
  __syncthreads();

  for (int kt = 0; kt < 24; ++kt) {
    if (kt < 23) {
      const int ln = (kt + 1) * 64;
      kr0 = *(const bf16x8v*)(Kbase + (size_t)(ln + sr) * 1024 + pch * 8);
      kr1 = *(const bf16x8v*)(Kbase + (size_t)(ln + 32 + sr) * 1024 + pch * 8);
      vr0 = *(const bf16x8v*)(Vbase + (size_t)sr * 1536 + ln + pch * 8);
      vr1 = *(const bf16x8v*)(Vbase + (size_t)(32 + sr) * 1536 + ln + pch * 8);
    }
    uint2 mwv = *(const uint2*)(mrow + kt * 2);

    f32x4 s[4];
    __builtin_amdgcn_s_setprio(1);
    #pragma unroll
    for (int nt = 0; nt < 4; ++nt) {
      const u16* kr = &Ks[(nt * 16 + c) * 64];
      bf16x8v k0 = *(const bf16x8v*)&kr[(g ^ cs) * 8];
      bf16x8v k1 = *(const bf16x8v*)&kr[((4 + g) ^ cs) * 8];
      f32x4 z = zf;
      z = __builtin_amdgcn_mfma_f32_16x16x32_bf16(k0, qf0, z, 0, 0, 0);
      z = __builtin_amdgcn_mfma_f32_16x16x32_bf16(k1, qf1, z, 0, 0, 0);
      s[nt] = z;
    }
    __builtin_amdgcn_s_setprio(0);

    uint64_t mq = (((uint64_t)mwv.y << 32) | (uint64_t)mwv.x) >> (4 * g);
    uint32_t mlo = (uint32_t)mq, mhi = (uint32_t)(mq >> 32);
    #pragma unroll
    for (int nt = 0; nt < 4; ++nt) {
      uint32_t msrc = (nt < 2) ? mlo : mhi;
      #pragma unroll
      for (int j = 0; j < 4; ++j) {
        float e = exp2f(s[nt][j]);
        float p = maskand(e, msrc, 16 * (nt & 1) + j);
        s[nt][j] = p;
        l += p;
      }
    }

    u16* pw = &Ps[wave][0];
    #pragma unroll
    for (int nt = 0; nt < 4; ++nt) {
      uint2 pk2;
      pk2.x = cvtpk(s[nt][0], s[nt][1]);
      pk2.y = cvtpk(s[nt][2], s[nt][3]);
      *(uint2*)&pw[c * 72 + nt * 16 + g * 4] = pk2;
    }
    bf16x8v pb0 = *(const bf16x8v*)&pw[c * 72 + g * 8];
    bf16x8v pb1 = *(const bf16x8v*)&pw[c * 72 + 32 + g * 8];
    __builtin_amdgcn_s_setprio(1);
    #pragma unroll
    for (int dt = 0; dt < 4; ++dt) {
      const u16* vr = &Vs[(dt * 16 + c) * 64];
      bf16x8v v0 = *(const bf16x8v*)&vr[(g ^ cs) * 8];
      bf16x8v v1 = *(const bf16x8v*)&vr[((4 + g) ^ cs) * 8];
      O[dt] = __builtin_amdgcn_mfma_f32_16x16x32_bf16(v0, pb0, O[dt], 0, 0, 0);
      O[dt] = __builtin_amdgcn_mfma_f32_16x16x32_bf16(v1, pb1, O[dt], 0, 0, 0);
    }
    __builtin_amdgcn_s_setprio(0);

    __syncthreads();                 // all waves done READING Ks/Vs
    if (kt < 23) {
      *(bf16x8v*)&Ks[sr * 64 + swz]        = kr0;
      *(bf16x8v*)&Ks[(32 + sr) * 64 + swz] = kr1;
      *(bf16x8v*)&Vs[sr * 64 + swz]        = vr0;
      *(bf16x8v*)&Vs[(32 + sr) * 64 + swz] = vr1;
      __syncthreads();
    }
  }

  float r = l;
  r += __shfl_xor(r, 16);
  r += __shfl_xor(r, 32);
  float inv = 1.f / r;
  size_t ro = (size_t)(b * 1024 + qw + c) * 1024 + h * 64;
  #pragma unroll
  for (int dt = 0; dt < 4; ++dt) {
    uint2 st;
    st.x = cvtpk(O[dt][0] * inv, O[dt][1] * inv);
    st.y = cvtpk(O[dt][2] * inv, O[dt][3] * inv);
    *(uint2*)&AO[ro + dt * 16 + 4 * g] = st;
  }
}

// ---------------------------------------------------------------------------
extern "C" void kernel_launch(void* const* d_in, const int* in_sizes, int n_in,
                              void* d_out, int out_size, void* d_ws, size_t ws_size,
                              hipStream_t stream) {
  (void)in_sizes; (void)n_in; (void)out_size; (void)ws_size;
  const float* hs = (const float*)d_in[0];
  const float* im = (const float*)d_in[1];
  const int*   mk = (const int*)d_in[2];
  const float* wq = (const float*)d_in[3];
  const float* wk = (const float*)d_in[4];
  const float* wv = (const float*)d_in[5];
  const float* uk = (const float*)d_in[6];
  const float* uv = (const float*)d_in[7];
  const float* wo = (const float*)d_in[8];

  char* ws = (char*)d_ws;
  u16* Hb  = (u16*)(ws + 0);          //  8,388,608 B  hidden bf16; reused as attn-out
  u16* Ib  = (u16*)(ws + 8388608);    //  4,194,304 B  image bf16
  u16* Wb  = (u16*)(ws + 12582912);   // 12,582,912 B  weights bf16 (wq wk wv uk uv wo)
  u16* Qb  = (u16*)(ws + 25165824);   //  8,388,608 B  Q token-major [4096][1024] (pre-scaled)
  u16* Kb  = (u16*)(ws + 33554432);   // 12,582,912 B  K concat [4][1536][1024]
  u16* Vtb = (u16*)(ws + 46137344);   // 12,582,912 B  V transposed [4][1024][1536]
  uint32_t* Mw = (uint32_t*)(ws + 58720256); // 786,432 B packed mask
  // total ws: 59,506,688 B

  prep<<<2048, 256, 0, stream>>>(mk, (const float4*)hs, (const float4*)im,
                                 (const float4*)wq, (const float4*)wk, (const float4*)wv,
                                 (const float4*)uk, (const float4*)uv, (const float4*)wo,
                                 Mw, Hb, Ib, Wb);
  gemm_qkv<<<256, 512, 0, stream>>>(Hb, Ib, Wb, Qb, Kb, Vtb);
  attn_kernel<<<1024, 256, 0, stream>>>(Qb, Kb, Vtb, Mw, Hb);
  gemm_out<<<256, 256, 0, stream>>>(Hb, Wb + 5 * 1048576, (float*)d_out);
}

// Round 10
// 158.940 us; speedup vs baseline: 1.0919x; 1.0066x over previous
//
#include <hip/hip_runtime.h>
#include <stdint.h>

// ---------------------------------------------------------------------------
// CustomGPT2MultiHeadAttention: B=4, S=1024, SI=512, D=1024, H=16, Dh=64
// Round 10: eliminate the prep cast pass. GEMMs read fp32 inputs directly
// (reg-staged float4 -> v_cvt_pk_bf16_f32 -> swizzled ds_write_b128), prep
// shrinks to mask_pack only. gemm_qkv: both operands fp32; gemm_out: A-side
// (attn-out bf16) keeps gl_lds, B-side (w_o) fp32 reg-staged.
// attn = round-4 known-good, unchanged.
// ---------------------------------------------------------------------------

typedef unsigned short u16;
typedef short bf16x8v __attribute__((ext_vector_type(8)));
typedef float f32x4 __attribute__((ext_vector_type(4)));

__device__ __forceinline__ u16 f2bf(float f) {
  union { float f; uint32_t u; } x; x.f = f;
  uint32_t r = x.u + 0x7FFFu + ((x.u >> 16) & 1u);   // round-to-nearest-even
  return (u16)(r >> 16);
}

// v_cvt_pk_bf16_f32: D[15:0]=bf16(a), D[31:16]=bf16(b), RNE
__device__ __forceinline__ uint32_t cvtpk(float a, float b) {
  uint32_t r;
  asm("v_cvt_pk_bf16_f32 %0, %1, %2" : "=v"(r) : "v"(a), "v"(b));
  return r;
}

// p = bit(msrc,off) ? e : 0   via sign-extended 1-bit field + AND (2 VALU)
__device__ __forceinline__ float maskand(float e, uint32_t msrc, int off) {
  uint32_t mm = (uint32_t)((int32_t)(msrc << (31 - off)) >> 31);
  union { float f; uint32_t u; } x; x.f = e; x.u &= mm; return x.f;
}

__device__ __forceinline__ void gl_lds16(const u16* g, u16* l) {
  __builtin_amdgcn_global_load_lds((const __attribute__((address_space(1))) unsigned int*)g,
                                   (__attribute__((address_space(3))) unsigned int*)l,
                                   16, 0, 0);
}

// ---------------------------------------------------------------------------
// 1) mask bit-pack: 196,608 words, 1 word (32 ints) per thread.
__global__ __launch_bounds__(256) void mask_pack(const int* __restrict__ mk,
                                                 uint32_t* __restrict__ Mw) {
  int w = blockIdx.x * 256 + threadIdx.x;   // grid 768 -> exactly 196,608
  const int4* p = (const int4*)(mk + (size_t)w * 32);
  uint32_t bits = 0;
  #pragma unroll
  for (int c = 0; c < 8; ++c) {
    int4 v = p[c];
    bits |= (uint32_t)(v.x != 0) << (4 * c);
    bits |= (uint32_t)(v.y != 0) << (4 * c + 1);
    bits |= (uint32_t)(v.z != 0) << (4 * c + 2);
    bits |= (uint32_t)(v.w != 0) << (4 * c + 3);
  }
  Mw[w] = bits;
}

// ---------------------------------------------------------------------------
// Fused QKV GEMM, 256x256 tile, BK=64, 512 thr / 8 waves (2Mx4N), dbuf,
// fp32 inputs with in-kernel cast:
//   tile kt: issue 8 fp32x4 A-loads(kt+1) | Bf reads + phases 0,1 |
//            cvt+write A->bx, issue 8 B-loads | phases 2,3 | cvt+write B->bx
//            | __syncthreads (drains lgkm; vmcnt already consumed by cvts).
// LDS layout/reader identical to R9 (pre-swizzled source chunk, linear dest).
// XCD-affine remap as R9.
__global__ __launch_bounds__(512, 2) void gemm_qkv(
    const float* __restrict__ Hs, const float* __restrict__ Im,
    const float* __restrict__ Wq, const float* __restrict__ Wk, const float* __restrict__ Wv,
    const float* __restrict__ Uk, const float* __restrict__ Uv,
    u16* __restrict__ Qd, u16* __restrict__ Kd, u16* __restrict__ Vd)
{
  __shared__ __align__(16) u16 As[2 * 16384];   // 64 KB
  __shared__ __align__(16) u16 Bs[2 * 16384];   // 64 KB
  const int hb = blockIdx.x;
  const int xcd = hb & 7, slot = hb >> 3;
  int bid = (slot < 24) ? xcd * 24 + slot : 192 + xcd * 8 + (slot - 24);
  const float *Ap, *Bp;
  int bm, bn, mode;
  if (bid < 192) { mode = 4; bm = (bid / 12) * 256; bn = (bid % 12) * 256;
                   Ap = Hs + (size_t)bm * 1024;
                   Bp = ((bn < 1024) ? Wq : (bn < 2048) ? Wk : Wv) + (size_t)(bn & 1023) * 1024; }
  else           { mode = 5; int r = bid - 192; bm = (r >> 3) * 256; bn = (r & 7) * 256;
                   Ap = Im + (size_t)bm * 1024;
                   Bp = ((bn < 1024) ? Uk : Uv) + (size_t)(bn & 1023) * 1024; }
  const int tid = threadIdx.x, lane = tid & 63, wave = tid >> 6;
  const int wr = wave >> 2, wc = wave & 3;      // 2M x 4N
  const int g = lane >> 4, c = lane & 15, cs = c & 7;
  const int srow = tid >> 3;                    // 0..63
  const int pch  = tid & 7;
  const int gsw  = (pch ^ (srow & 7)) * 8;      // pre-swizzled global elem chunk

  f32x4 zf = {0.f, 0.f, 0.f, 0.f};
  f32x4 acc[8][4];
  #pragma unroll
  for (int f = 0; f < 8; ++f)
    #pragma unroll
    for (int nf = 0; nf < 4; ++nf) acc[f][nf] = zf;

  float4 sa[4][2], sb[4][2];

  #define LOAD_A(kt)                                                               \
    _Pragma("unroll")                                                              \
    for (int j_ = 0; j_ < 4; ++j_) {                                               \
      const float* p_ = Ap + (size_t)(j_ * 64 + srow) * 1024 + (kt) * 64 + gsw;    \
      sa[j_][0] = *(const float4*)p_;                                              \
      sa[j_][1] = *(const float4*)(p_ + 4);                                        \
    }
  #define LOAD_B(kt)                                                               \
    _Pragma("unroll")                                                              \
    for (int j_ = 0; j_ < 4; ++j_) {                                               \
      const float* p_ = Bp + (size_t)(j_ * 64 + srow) * 1024 + (kt) * 64 + gsw;    \
      sb[j_][0] = *(const float4*)p_;                                              \
      sb[j_][1] = *(const float4*)(p_ + 4);                                        \
    }
  #define CVT_A(buf)                                                               \
    _Pragma("unroll")                                                              \
    for (int j_ = 0; j_ < 4; ++j_) {                                               \
      uint4 w_;                                                                    \
      w_.x = cvtpk(sa[j_][0].x, sa[j_][0].y);                                      \
      w_.y = cvtpk(sa[j_][0].z, sa[j_][0].w);                                      \
      w_.z = cvtpk(sa[j_][1].x, sa[j_][1].y);                                      \
      w_.w = cvtpk(sa[j_][1].z, sa[j_][1].w);                                      \
      *(uint4*)&As[(buf) + (j_ * 64 + srow) * 64 + pch * 8] = w_;                  \
    }
  #define CVT_B(buf)                                                               \
    _Pragma("unroll")                                                              \
    for (int j_ = 0; j_ < 4; ++j_) {                                               \
      uint4 w_;                                                                    \
      w_.x = cvtpk(sb[j_][0].x, sb[j_][0].y);                                      \
      w_.y = cvtpk(sb[j_][0].z, sb[j_][0].w);                                      \
      w_.z = cvtpk(sb[j_][1].x, sb[j_][1].y);                                      \
      w_.w = cvtpk(sb[j_][1].z, sb[j_][1].w);                                      \
      *(uint4*)&Bs[(buf) + (j_ * 64 + srow) * 64 + pch * 8] = w_;                  \
    }

  // prologue: tile 0 -> buf 0
  LOAD_A(0); LOAD_B(0);
  CVT_A(0);  CVT_B(0);
  __syncthreads();

  for (int kt = 0; kt < 16; ++kt) {
    const int bc = (kt & 1) * 16384;
    const int bx = bc ^ 16384;
    if (kt < 15) LOAD_A(kt + 1);       // fire-and-forget, lands during phases 0-1

    bf16x8v Bf[4][2];
    #pragma unroll
    for (int nf = 0; nf < 4; ++nf)
      #pragma unroll
      for (int ks = 0; ks < 2; ++ks)
        Bf[nf][ks] = *(const bf16x8v*)&Bs[bc + (wc * 64 + nf * 16 + c) * 64 + ((ks * 4 + g) ^ cs) * 8];

    #pragma unroll
    for (int p = 0; p < 4; ++p) {
      bf16x8v Af[2][2];
      #pragma unroll
      for (int i = 0; i < 2; ++i)
        #pragma unroll
        for (int ks = 0; ks < 2; ++ks)
          Af[i][ks] = *(const bf16x8v*)&As[bc + (wr * 128 + (p * 2 + i) * 16 + c) * 64 + ((ks * 4 + g) ^ cs) * 8];
      __builtin_amdgcn_s_setprio(1);
      #pragma unroll
      for (int i = 0; i < 2; ++i)
        #pragma unroll
        for (int nf = 0; nf < 4; ++nf)
          #pragma unroll
          for (int ks = 0; ks < 2; ++ks)
            acc[p * 2 + i][nf] =
              __builtin_amdgcn_mfma_f32_16x16x32_bf16(Af[i][ks], Bf[nf][ks], acc[p * 2 + i][nf], 0, 0, 0);
      __builtin_amdgcn_s_setprio(0);
      if (p == 1 && kt < 15) {
        __builtin_amdgcn_sched_barrier(0);   // keep cvt below phases 0-1
        CVT_A(bx);                           // A regs landed; write buf bx (idle this tile)
        LOAD_B(kt + 1);                      // B loads land during phases 2-3
        __builtin_amdgcn_sched_barrier(0);
      }
    }
    if (kt < 15) {
      __builtin_amdgcn_sched_barrier(0);
      CVT_B(bx);
    }
    __syncthreads();                         // reads of bc done; bx writes visible
  }
  #undef LOAD_A
  #undef LOAD_B
  #undef CVT_A
  #undef CVT_B

  // epilogue: C row = 4*g + j, col = c
  #pragma unroll
  for (int f = 0; f < 8; ++f) {
    #pragma unroll
    for (int nf = 0; nf < 4; ++nf) {
      #pragma unroll
      for (int j = 0; j < 4; ++j) {
        int gm = bm + wr * 128 + f * 16 + 4 * g + j;
        int gn = bn + wc * 64 + nf * 16 + c;
        float v = acc[f][nf][j];
        if (mode == 4) {
          int b_ = gm >> 10, s_ = gm & 1023;
          if (gn < 1024)      Qd[(size_t)gm * 1024 + gn] = f2bf(v * 0.18033688011112042f);
          else if (gn < 2048) Kd[(size_t)(b_ * 1536 + s_) * 1024 + (gn - 1024)] = f2bf(v);
          else                Vd[(size_t)(b_ * 1024 + (gn - 2048)) * 1536 + s_] = f2bf(v);
        } else {
          int b_ = gm >> 9, s_ = gm & 511;
          if (gn < 1024) Kd[(size_t)(b_ * 1536 + 1024 + s_) * 1024 + gn] = f2bf(v);
          else           Vd[(size_t)(b_ * 1024 + (gn - 1024)) * 1536 + 1024 + s_] = f2bf(v);
        }
      }
    }
  }
}

// ---------------------------------------------------------------------------
// out-proj GEMM: 128x128 tile, BK=64, 256 thr / 4 waves (2x2), dbuf.
// A = attn-out bf16 via gl_lds (pre-swizzled source); B = w_o fp32 reg-staged
// with in-kernel cast. XCD-affine 1D grid (XCD x: 4 row-groups x 8 cols).
__global__ __launch_bounds__(256) void gemm_out(const u16* __restrict__ A, const float* __restrict__ Bw,
                                                float* __restrict__ Cout)
{
  __shared__ __align__(16) u16 As2[2 * 8192];   // 32 KB
  __shared__ __align__(16) u16 Bs2[2 * 8192];   // 32 KB
  const int hb = blockIdx.x;
  const int xcd = hb & 7, slot = hb >> 3;       // slot 0..31
  const int rg = xcd * 4 + (slot >> 3);         // 0..31
  const int cg = slot & 7;                      // 0..7
  const int bm = rg * 128, bn = cg * 128;
  const int tid  = threadIdx.x;
  const int lane = tid & 63, wave = tid >> 6;
  const int wr = wave >> 1, wc = wave & 1;
  const int g = lane >> 4, c = lane & 15, cs = c & 7;
  const int sr  = tid >> 3;                     // 0..31
  const int pch = tid & 7;
  const int gsw = (pch ^ (sr & 7)) * 8;

  f32x4 zf = {0.f, 0.f, 0.f, 0.f};
  f32x4 acc[4][4];
  #pragma unroll
  for (int mi = 0; mi < 4; ++mi)
    #pragma unroll
    for (int ni = 0; ni < 4; ++ni) acc[mi][ni] = zf;

  float4 sb[4][2];

  #define STG_A(buf, kt)                                                           \
    _Pragma("unroll")                                                              \
    for (int q_ = 0; q_ < 4; ++q_) {                                               \
      int row_ = q_ * 32 + sr;                                                     \
      gl_lds16(A + (size_t)(bm + row_) * 1024 + (kt) * 64 + gsw,                   \
               &As2[(buf) + row_ * 64 + pch * 8]);                                 \
    }
  #define LOAD_B(kt)                                                               \
    _Pragma("unroll")                                                              \
    for (int q_ = 0; q_ < 4; ++q_) {                                               \
      const float* p_ = Bw + (size_t)(bn + q_ * 32 + sr) * 1024 + (kt) * 64 + gsw; \
      sb[q_][0] = *(const float4*)p_;                                              \
      sb[q_][1] = *(const float4*)(p_ + 4);                                        \
    }
  #define CVT_B(buf)                                                               \
    _Pragma("unroll")                                                              \
    for (int q_ = 0; q_ < 4; ++q_) {                                               \
      uint4 w_;                                                                    \
      w_.x = cvtpk(sb[q_][0].x, sb[q_][0].y);                                      \
      w_.y = cvtpk(sb[q_][0].z, sb[q_][0].w);                                      \
      w_.z = cvtpk(sb[q_][1].x, sb[q_][1].y);                                      \
      w_.w = cvtpk(sb[q_][1].z, sb[q_][1].w);                                      \
      *(uint4*)&Bs2[(buf) + (q_ * 32 + sr) * 64 + pch * 8] = w_;                   \
    }

  STG_A(0, 0);
  LOAD_B(0);
  CVT_B(0);
  __syncthreads();

  for (int kt = 0; kt < 16; ++kt) {
    const int bc = (kt & 1) * 8192;
    const int bx = bc ^ 8192;
    if (kt < 15) { STG_A(bx, kt + 1); LOAD_B(kt + 1); }

    #pragma unroll
    for (int ks = 0; ks < 2; ++ks) {
      bf16x8v af[4], bfr[4];
      #pragma unroll
      for (int mi = 0; mi < 4; ++mi)
        af[mi] = *(const bf16x8v*)&As2[bc + (wr * 64 + mi * 16 + c) * 64 + ((ks * 4 + g) ^ cs) * 8];
      #pragma unroll
      for (int ni = 0; ni < 4; ++ni)
        bfr[ni] = *(const bf16x8v*)&Bs2[bc + (wc * 64 + ni * 16 + c) * 64 + ((ks * 4 + g) ^ cs) * 8];
      __builtin_amdgcn_s_setprio(1);
      #pragma unroll
      for (int mi = 0; mi < 4; ++mi)
        #pragma unroll
        for (int ni = 0; ni < 4; ++ni)
          acc[mi][ni] = __builtin_amdgcn_mfma_f32_16x16x32_bf16(af[mi], bfr[ni], acc[mi][ni], 0, 0, 0);
      __builtin_amdgcn_s_setprio(0);
    }
    if (kt < 15) {
      __builtin_amdgcn_sched_barrier(0);
      CVT_B(bx);
    }
    __syncthreads();   // drains gl_lds vmcnt (had full compute phase) + ds writes
  }
  #undef STG_A
  #undef LOAD_B
  #undef CVT_B

  #pragma unroll
  for (int mi = 0; mi < 4; ++mi)
    #pragma unroll
    for (int ni = 0; ni < 4; ++ni)
      #pragma unroll
      for (int j = 0; j < 4; ++j) {
        int gm = bm + wr * 64 + mi * 16 + 4 * g + j;
        int gn = bn + wc * 64 + ni * 16 + c;
        Cout[(size_t)gm * 1024 + gn] = acc[mi][ni][j];
      }
}

// ---------------------------------------------------------------------------
// flash attention, swapped QK^T, max-free softmax (round-4 known-good)
__global__ __launch_bounds__(256) void attn_kernel(const u16* __restrict__ Q, const u16* __restrict__ Kc,
                                                   const u16* __restrict__ Vt,
                                                   const uint32_t* __restrict__ Mw,
                                                   u16* __restrict__ AO)
{
  const int bid = blockIdx.x;
  const int grp = bid & 63;           // (b,h) group; XCD = bid%8 = grp%8
  const int qt  = bid >> 6;
  const int h = grp & 15, b = grp >> 4;
  const int q0 = qt * 64;
  const int tid = threadIdx.x, lane = tid & 63, wave = tid >> 6;
  const int g = lane >> 4, c = lane & 15;
  const int qw = q0 + wave * 16;

  __shared__ __align__(16) u16 Ks[64 * 64];      // 8 KB
  __shared__ __align__(16) u16 Vs[64 * 64];      // 8 KB  [d][l]
  __shared__ __align__(16) u16 Ps[4][16 * 72];   // 9 KB  per-wave P, padded

  bf16x8v qf0, qf1;
  {
    const u16* qp = Q + (size_t)(b * 1024 + qw + c) * 1024 + h * 64 + g * 8;
    qf0 = *(const bf16x8v*)qp;
    qf1 = *(const bf16x8v*)(qp + 32);
  }
  f32x4 zf = {0.f, 0.f, 0.f, 0.f};
  f32x4 O[4];                       // O^T frag: [d=dt*16+4g+j][q=c]
  float l = 0.f;                    // per-lane partial denominator
  #pragma unroll
  for (int dt = 0; dt < 4; ++dt) O[dt] = zf;

  const int sr  = tid >> 3;         // 0..31
  const int pch = tid & 7;
  const int swz = (pch ^ (sr & 7)) * 8;   // write-side XOR swizzle
  const int cs  = c & 7;
  const u16* Kbase = Kc + (size_t)(b * 1536) * 1024 + h * 64;
  const u16* Vbase = Vt + (size_t)(b * 1024 + h * 64) * 1536;
  const uint32_t* mrow = Mw + (size_t)(b * 1024 + qw + c) * 48;

  bf16x8v kr0, kr1, vr0, vr1;
  kr0 = *(const bf16x8v*)(Kbase + (size_t)sr * 1024 + pch * 8);
  kr1 = *(const bf16x8v*)(Kbase + (size_t)(32 + sr) * 1024 + pch * 8);
  vr0 = *(const bf16x8v*)(Vbase + (size_t)sr * 1536 + pch * 8);
  vr1 = *(const bf16x8v*)(Vbase + (size_t)(32 + sr) * 1536 + pch * 8);
  *(bf16x8v*)&Ks[sr * 64 + swz]        = kr0;
  *(bf16x8v*)&Ks[(32 + sr) * 64 + swz] = kr1;
  *(bf16x8v*)&Vs[sr * 64 + swz]        = vr0;
  *(bf16x8v*)&Vs[(32 + sr) * 64 + swz] = vr1;
  __syncthreads();

  for (int kt = 0; kt < 24; ++kt) {
    if (kt < 23) {
      const int ln = (kt + 1) * 64;
      kr0 = *(const bf16x8v*)(Kbase + (size_t)(ln + sr) * 1024 + pch * 8);
      kr1 = *(const bf16x8v*)(Kbase + (size_t)(ln + 32 + sr) * 1024 + pch * 8);
      vr0 = *(const bf16x8v*)(Vbase + (size_t)sr * 1536 + ln + pch * 8);
      vr1 = *(const bf16x8v*)(Vbase + (size_t)(32 + sr) * 1536 + ln + pch * 8);
    }
    uint2 mwv = *(const uint2*)(mrow + kt * 2);

    f32x4 s[4];
    __builtin_amdgcn_s_setprio(1);
    #pragma unroll
    for (int nt = 0; nt < 4; ++nt) {
      const u16* kr = &Ks[(nt * 16 + c) * 64];
      bf16x8v k0 = *(const bf16x8v*)&kr[(g ^ cs) * 8];
      bf16x8v k1 = *(const bf16x8v*)&kr[((4 + g) ^ cs) * 8];
      f32x4 z = zf;
      z = __builtin_amdgcn_mfma_f32_16x16x32_bf16(k0, qf0, z, 0, 0, 0);
      z = __builtin_amdgcn_mfma_f32_16x16x32_bf16(k1, qf1, z, 0, 0, 0);
      s[nt] = z;
    }
    __builtin_amdgcn_s_setprio(0);

    uint64_t mq = (((uint64_t)mwv.y << 32) | (uint64_t)mwv.x) >> (4 * g);
    uint32_t mlo = (uint32_t)mq, mhi = (uint32_t)(mq >> 32);
    #pragma unroll
    for (int nt = 0; nt < 4; ++nt) {
      uint32_t msrc = (nt < 2) ? mlo : mhi;
      #pragma unroll
      for (int j = 0; j < 4; ++j) {
        float e = exp2f(s[nt][j]);
        float p = maskand(e, msrc, 16 * (nt & 1) + j);
        s[nt][j] = p;
        l += p;
      }
    }

    u16* pw = &Ps[wave][0];
    #pragma unroll
    for (int nt = 0; nt < 4; ++nt) {
      uint2 pk2;
      pk2.x = cvtpk(s[nt][0], s[nt][1]);
      pk2.y = cvtpk(s[nt][2], s[nt][3]);
      *(uint2*)&pw[c * 72 + nt * 16 + g * 4] = pk2;
    }
    bf16x8v pb0 = *(const bf16x8v*)&pw[c * 72 + g * 8];
    bf16x8v pb1 = *(const bf16x8v*)&pw[c * 72 + 32 + g * 8];
    __builtin_amdgcn_s_setprio(1);
    #pragma unroll
    for (int dt = 0; dt < 4; ++dt) {
      const u16* vr = &Vs[(dt * 16 + c) * 64];
      bf16x8v v0 = *(const bf16x8v*)&vr[(g ^ cs) * 8];
      bf16x8v v1 = *(const bf16x8v*)&vr[((4 + g) ^ cs) * 8];
      O[dt] = __builtin_amdgcn_mfma_f32_16x16x32_bf16(v0, pb0, O[dt], 0, 0, 0);
      O[dt] = __builtin_amdgcn_mfma_f32_16x16x32_bf16(v1, pb1, O[dt], 0, 0, 0);
    }
    __builtin_amdgcn_s_setprio(0);

    __syncthreads();                 // all waves done READING Ks/Vs
    if (kt < 23) {
      *(bf16x8v*)&Ks[sr * 64 + swz]        = kr0;
      *(bf16x8v*)&Ks[(32 + sr) * 64 + swz] = kr1;
      *(bf16x8v*)&Vs[sr * 64 + swz]        = vr0;
      *(bf16x8v*)&Vs[(32 + sr) * 64 + swz] = vr1;
      __syncthreads();
    }
  }

  float r = l;
  r += __shfl_xor(r, 16);
  r += __shfl_xor(r, 32);
  float inv = 1.f / r;
  size_t ro = (size_t)(b * 1024 + qw + c) * 1024 + h * 64;
  #pragma unroll
  for (int dt = 0; dt < 4; ++dt) {
    uint2 st;
    st.x = cvtpk(O[dt][0] * inv, O[dt][1] * inv);
    st.y = cvtpk(O[dt][2] * inv, O[dt][3] * inv);
    *(uint2*)&AO[ro + dt * 16 + 4 * g] = st;
  }
}

// ---------------------------------------------------------------------------
extern "C" void kernel_launch(void* const* d_in, const int* in_sizes, int n_in,
                              void* d_out, int out_size, void* d_ws, size_t ws_size,
                              hipStream_t stream) {
  (void)in_sizes; (void)n_in; (void)out_size; (void)ws_size;
  const float* hs = (const float*)d_in[0];
  const float* im = (const float*)d_in[1];
  const int*   mk = (const int*)d_in[2];
  const float* wq = (const float*)d_in[3];
  const float* wk = (const float*)d_in[4];
  const float* wv = (const float*)d_in[5];
  const float* uk = (const float*)d_in[6];
  const float* uv = (const float*)d_in[7];
  const float* wo = (const float*)d_in[8];

  char* ws = (char*)d_ws;
  u16* Qb  = (u16*)(ws + 0);          //  8,388,608 B  Q token-major [4096][1024] (pre-scaled)
  u16* Kb  = (u16*)(ws + 8388608);    // 12,582,912 B  K concat [4][1536][1024]
  u16* Vtb = (u16*)(ws + 20971520);   // 12,582,912 B  V transposed [4][1024][1536]
  u16* AO  = (u16*)(ws + 33554432);   //  8,388,608 B  attn out bf16 [4096][1024]
  uint32_t* Mw = (uint32_t*)(ws + 41943040); // 786,432 B packed mask
  // total ws: 42,729,472 B

  mask_pack<<<768, 256, 0, stream>>>(mk, Mw);
  gemm_qkv<<<256, 512, 0, stream>>>(hs, im, wq, wk, wv, uk, uv, Qb, Kb, Vtb);
  attn_kernel<<<1024, 256, 0, stream>>>(Qb, Kb, Vtb, Mw, AO);
  gemm_out<<<256, 256, 0, stream>>>(AO, wo, (float*)d_out);
}

// Round 11
// 133.738 us; speedup vs baseline: 1.2976x; 1.1884x over previous
//
#include <hip/hip_runtime.h>
#include <stdint.h>

// ---------------------------------------------------------------------------
// CustomGPT2MultiHeadAttention: B=4, S=1024, SI=512, D=1024, H=16, Dh=64
// Round 11: (1) V-epilogue vectorized — lane holds 4 consecutive s-values of
// one Vt row -> uint2 store (4x fewer transactions on the 3KB-stride scatter);
// block-uniform region branches (bn is 256-aligned). (2) mask_pack fused into
// gemm_qkv prologue (3 dispatches total). attn/gemm_out = round-10.
// ---------------------------------------------------------------------------

typedef unsigned short u16;
typedef short bf16x8v __attribute__((ext_vector_type(8)));
typedef float f32x4 __attribute__((ext_vector_type(4)));

__device__ __forceinline__ u16 f2bf(float f) {
  union { float f; uint32_t u; } x; x.f = f;
  uint32_t r = x.u + 0x7FFFu + ((x.u >> 16) & 1u);   // round-to-nearest-even
  return (u16)(r >> 16);
}

// v_cvt_pk_bf16_f32: D[15:0]=bf16(a), D[31:16]=bf16(b), RNE
__device__ __forceinline__ uint32_t cvtpk(float a, float b) {
  uint32_t r;
  asm("v_cvt_pk_bf16_f32 %0, %1, %2" : "=v"(r) : "v"(a), "v"(b));
  return r;
}

// p = bit(msrc,off) ? e : 0   via sign-extended 1-bit field + AND (2 VALU)
__device__ __forceinline__ float maskand(float e, uint32_t msrc, int off) {
  uint32_t mm = (uint32_t)((int32_t)(msrc << (31 - off)) >> 31);
  union { float f; uint32_t u; } x; x.f = e; x.u &= mm; return x.f;
}

__device__ __forceinline__ void gl_lds16(const u16* g, u16* l) {
  __builtin_amdgcn_global_load_lds((const __attribute__((address_space(1))) unsigned int*)g,
                                   (__attribute__((address_space(3))) unsigned int*)l,
                                   16, 0, 0);
}

// ---------------------------------------------------------------------------
// Fused QKV GEMM, 256x256 tile, BK=64, 512 thr / 8 waves (2Mx4N), dbuf,
// fp32 inputs with in-kernel cast (R10 schedule), + fused mask bit-pack in
// the prologue, + vectorized V-epilogue. XCD-affine remap as R9/R10.
__global__ __launch_bounds__(512, 2) void gemm_qkv(
    const float* __restrict__ Hs, const float* __restrict__ Im,
    const float* __restrict__ Wq, const float* __restrict__ Wk, const float* __restrict__ Wv,
    const float* __restrict__ Uk, const float* __restrict__ Uv,
    const int* __restrict__ Mk,
    u16* __restrict__ Qd, u16* __restrict__ Kd, u16* __restrict__ Vd,
    uint32_t* __restrict__ Mw)
{
  __shared__ __align__(16) u16 As[2 * 16384];   // 64 KB
  __shared__ __align__(16) u16 Bs[2 * 16384];   // 64 KB
  const int hb = blockIdx.x;
  const int xcd = hb & 7, slot = hb >> 3;
  int bid = (slot < 24) ? xcd * 24 + slot : 192 + xcd * 8 + (slot - 24);
  const float *Ap, *Bp;
  int bm, bn, mode;
  if (bid < 192) { mode = 4; bm = (bid / 12) * 256; bn = (bid % 12) * 256;
                   Ap = Hs + (size_t)bm * 1024;
                   Bp = ((bn < 1024) ? Wq : (bn < 2048) ? Wk : Wv) + (size_t)(bn & 1023) * 1024; }
  else           { mode = 5; int r = bid - 192; bm = (r >> 3) * 256; bn = (r & 7) * 256;
                   Ap = Im + (size_t)bm * 1024;
                   Bp = ((bn < 1024) ? Uk : Uv) + (size_t)(bn & 1023) * 1024; }
  const int tid = threadIdx.x, lane = tid & 63, wave = tid >> 6;
  const int wr = wave >> 2, wc = wave & 3;      // 2M x 4N
  const int g = lane >> 4, c = lane & 15, cs = c & 7;
  const int srow = tid >> 3;                    // 0..63
  const int pch  = tid & 7;
  const int gsw  = (pch ^ (srow & 7)) * 8;      // pre-swizzled global elem chunk

  f32x4 zf = {0.f, 0.f, 0.f, 0.f};
  f32x4 acc[8][4];
  #pragma unroll
  for (int f = 0; f < 8; ++f)
    #pragma unroll
    for (int nf = 0; nf < 4; ++nf) acc[f][nf] = zf;

  float4 sa[4][2], sb[4][2];

  #define LOAD_A(kt)                                                               \
    _Pragma("unroll")                                                              \
    for (int j_ = 0; j_ < 4; ++j_) {                                               \
      const float* p_ = Ap + (size_t)(j_ * 64 + srow) * 1024 + (kt) * 64 + gsw;    \
      sa[j_][0] = *(const float4*)p_;                                              \
      sa[j_][1] = *(const float4*)(p_ + 4);                                        \
    }
  #define LOAD_B(kt)                                                               \
    _Pragma("unroll")                                                              \
    for (int j_ = 0; j_ < 4; ++j_) {                                               \
      const float* p_ = Bp + (size_t)(j_ * 64 + srow) * 1024 + (kt) * 64 + gsw;    \
      sb[j_][0] = *(const float4*)p_;                                              \
      sb[j_][1] = *(const float4*)(p_ + 4);                                        \
    }
  #define CVT_A(buf)                                                               \
    _Pragma("unroll")                                                              \
    for (int j_ = 0; j_ < 4; ++j_) {                                               \
      uint4 w_;                                                                    \
      w_.x = cvtpk(sa[j_][0].x, sa[j_][0].y);                                      \
      w_.y = cvtpk(sa[j_][0].z, sa[j_][0].w);                                      \
      w_.z = cvtpk(sa[j_][1].x, sa[j_][1].y);                                      \
      w_.w = cvtpk(sa[j_][1].z, sa[j_][1].w);                                      \
      *(uint4*)&As[(buf) + (j_ * 64 + srow) * 64 + pch * 8] = w_;                  \
    }
  #define CVT_B(buf)                                                               \
    _Pragma("unroll")                                                              \
    for (int j_ = 0; j_ < 4; ++j_) {                                               \
      uint4 w_;                                                                    \
      w_.x = cvtpk(sb[j_][0].x, sb[j_][0].y);                                      \
      w_.y = cvtpk(sb[j_][0].z, sb[j_][0].w);                                      \
      w_.z = cvtpk(sb[j_][1].x, sb[j_][1].y);                                      \
      w_.w = cvtpk(sb[j_][1].z, sb[j_][1].w);                                      \
      *(uint4*)&Bs[(buf) + (j_ * 64 + srow) * 64 + pch * 8] = w_;                  \
    }

  // prologue: issue tile-0 loads, then pack mask (overlaps tile-0 latency)
  LOAD_A(0); LOAD_B(0);
  {
    const int fid = hb * 512 + tid;   // 131,072 threads; 196,608 words
    #pragma unroll 1
    for (int w = fid; w < 196608; w += 131072) {
      const int4* p = (const int4*)(Mk + (size_t)w * 32);
      uint32_t bits = 0;
      #pragma unroll 1
      for (int h_ = 0; h_ < 2; ++h_) {       // two batches of 4 int4 (reg cap)
        int4 v0 = p[h_ * 4 + 0], v1 = p[h_ * 4 + 1];
        int4 v2 = p[h_ * 4 + 2], v3 = p[h_ * 4 + 3];
        int bo = h_ * 16;
        bits |= (uint32_t)(v0.x != 0) << (bo + 0);
        bits |= (uint32_t)(v0.y != 0) << (bo + 1);
        bits |= (uint32_t)(v0.z != 0) << (bo + 2);
        bits |= (uint32_t)(v0.w != 0) << (bo + 3);
        bits |= (uint32_t)(v1.x != 0) << (bo + 4);
        bits |= (uint32_t)(v1.y != 0) << (bo + 5);
        bits |= (uint32_t)(v1.z != 0) << (bo + 6);
        bits |= (uint32_t)(v1.w != 0) << (bo + 7);
        bits |= (uint32_t)(v2.x != 0) << (bo + 8);
        bits |= (uint32_t)(v2.y != 0) << (bo + 9);
        bits |= (uint32_t)(v2.z != 0) << (bo + 10);
        bits |= (uint32_t)(v2.w != 0) << (bo + 11);
        bits |= (uint32_t)(v3.x != 0) << (bo + 12);
        bits |= (uint32_t)(v3.y != 0) << (bo + 13);
        bits |= (uint32_t)(v3.z != 0) << (bo + 14);
        bits |= (uint32_t)(v3.w != 0) << (bo + 15);
      }
      Mw[w] = bits;
    }
  }
  CVT_A(0);  CVT_B(0);
  __syncthreads();

  for (int kt = 0; kt < 16; ++kt) {
    const int bc = (kt & 1) * 16384;
    const int bx = bc ^ 16384;
    if (kt < 15) LOAD_A(kt + 1);       // fire-and-forget, lands during phases 0-1

    bf16x8v Bf[4][2];
    #pragma unroll
    for (int nf = 0; nf < 4; ++nf)
      #pragma unroll
      for (int ks = 0; ks < 2; ++ks)
        Bf[nf][ks] = *(const bf16x8v*)&Bs[bc + (wc * 64 + nf * 16 + c) * 64 + ((ks * 4 + g) ^ cs) * 8];

    #pragma unroll
    for (int p = 0; p < 4; ++p) {
      bf16x8v Af[2][2];
      #pragma unroll
      for (int i = 0; i < 2; ++i)
        #pragma unroll
        for (int ks = 0; ks < 2; ++ks)
          Af[i][ks] = *(const bf16x8v*)&As[bc + (wr * 128 + (p * 2 + i) * 16 + c) * 64 + ((ks * 4 + g) ^ cs) * 8];
      __builtin_amdgcn_s_setprio(1);
      #pragma unroll
      for (int i = 0; i < 2; ++i)
        #pragma unroll
        for (int nf = 0; nf < 4; ++nf)
          #pragma unroll
          for (int ks = 0; ks < 2; ++ks)
            acc[p * 2 + i][nf] =
              __builtin_amdgcn_mfma_f32_16x16x32_bf16(Af[i][ks], Bf[nf][ks], acc[p * 2 + i][nf], 0, 0, 0);
      __builtin_amdgcn_s_setprio(0);
      if (p == 1 && kt < 15) {
        __builtin_amdgcn_sched_barrier(0);   // keep cvt below phases 0-1
        CVT_A(bx);                           // A regs landed; write buf bx
        LOAD_B(kt + 1);                      // B loads land during phases 2-3
        __builtin_amdgcn_sched_barrier(0);
      }
    }
    if (kt < 15) {
      __builtin_amdgcn_sched_barrier(0);
      CVT_B(bx);
    }
    __syncthreads();                         // reads of bc done; bx writes visible
  }
  #undef LOAD_A
  #undef LOAD_B
  #undef CVT_A
  #undef CVT_B

  // epilogue — whole block is ONE region (bn is 256-aligned):
  //   Q/K: 2B stores (16-lane 32B segments). V: uint2 (4 consecutive s per
  //   lane along Vt's contiguous axis) — 4x fewer scatter transactions.
  const int gn0 = bn + wc * 64;
  if (mode == 4) {
    if (bn < 1024) {
      #pragma unroll
      for (int f = 0; f < 8; ++f)
        #pragma unroll
        for (int nf = 0; nf < 4; ++nf) {
          int gm = bm + wr * 128 + f * 16 + 4 * g;
          int gn = gn0 + nf * 16 + c;
          #pragma unroll
          for (int j = 0; j < 4; ++j)
            Qd[(size_t)(gm + j) * 1024 + gn] = f2bf(acc[f][nf][j] * 0.18033688011112042f);
        }
    } else if (bn < 2048) {
      #pragma unroll
      for (int f = 0; f < 8; ++f)
        #pragma unroll
        for (int nf = 0; nf < 4; ++nf) {
          int gm = bm + wr * 128 + f * 16 + 4 * g;
          int b_ = gm >> 10, s_ = gm & 1023;
          int gn = gn0 - 1024 + nf * 16 + c;
          #pragma unroll
          for (int j = 0; j < 4; ++j)
            Kd[(size_t)(b_ * 1536 + s_ + j) * 1024 + gn] = f2bf(acc[f][nf][j]);
        }
    } else {
      #pragma unroll
      for (int f = 0; f < 8; ++f)
        #pragma unroll
        for (int nf = 0; nf < 4; ++nf) {
          int gm = bm + wr * 128 + f * 16 + 4 * g;
          int b_ = gm >> 10, s_ = gm & 1023;
          int d_ = gn0 - 2048 + nf * 16 + c;
          uint2 st;
          st.x = cvtpk(acc[f][nf][0], acc[f][nf][1]);
          st.y = cvtpk(acc[f][nf][2], acc[f][nf][3]);
          *(uint2*)&Vd[(size_t)(b_ * 1024 + d_) * 1536 + s_] = st;
        }
    }
  } else {
    if (bn < 1024) {
      #pragma unroll
      for (int f = 0; f < 8; ++f)
        #pragma unroll
        for (int nf = 0; nf < 4; ++nf) {
          int gm = bm + wr * 128 + f * 16 + 4 * g;
          int b_ = gm >> 9, s_ = gm & 511;
          int gn = gn0 + nf * 16 + c;
          #pragma unroll
          for (int j = 0; j < 4; ++j)
            Kd[(size_t)(b_ * 1536 + 1024 + s_ + j) * 1024 + gn] = f2bf(acc[f][nf][j]);
        }
    } else {
      #pragma unroll
      for (int f = 0; f < 8; ++f)
        #pragma unroll
        for (int nf = 0; nf < 4; ++nf) {
          int gm = bm + wr * 128 + f * 16 + 4 * g;
          int b_ = gm >> 9, s_ = gm & 511;
          int d_ = gn0 - 1024 + nf * 16 + c;
          uint2 st;
          st.x = cvtpk(acc[f][nf][0], acc[f][nf][1]);
          st.y = cvtpk(acc[f][nf][2], acc[f][nf][3]);
          *(uint2*)&Vd[(size_t)(b_ * 1024 + d_) * 1536 + 1024 + s_] = st;
        }
    }
  }
}

// ---------------------------------------------------------------------------
// out-proj GEMM (round-10): 128x128 tile, BK=64, 256 thr / 4 waves, dbuf.
// A = attn-out bf16 via gl_lds; B = w_o fp32 reg-staged with in-kernel cast.
__global__ __launch_bounds__(256) void gemm_out(const u16* __restrict__ A, const float* __restrict__ Bw,
                                                float* __restrict__ Cout)
{
  __shared__ __align__(16) u16 As2[2 * 8192];   // 32 KB
  __shared__ __align__(16) u16 Bs2[2 * 8192];   // 32 KB
  const int hb = blockIdx.x;
  const int xcd = hb & 7, slot = hb >> 3;       // slot 0..31
  const int rg = xcd * 4 + (slot >> 3);         // 0..31
  const int cg = slot & 7;                      // 0..7
  const int bm = rg * 128, bn = cg * 128;
  const int tid  = threadIdx.x;
  const int lane = tid & 63, wave = tid >> 6;
  const int wr = wave >> 1, wc = wave & 1;
  const int g = lane >> 4, c = lane & 15, cs = c & 7;
  const int sr  = tid >> 3;                     // 0..31
  const int pch = tid & 7;
  const int gsw = (pch ^ (sr & 7)) * 8;

  f32x4 zf = {0.f, 0.f, 0.f, 0.f};
  f32x4 acc[4][4];
  #pragma unroll
  for (int mi = 0; mi < 4; ++mi)
    #pragma unroll
    for (int ni = 0; ni < 4; ++ni) acc[mi][ni] = zf;

  float4 sb[4][2];

  #define STG_A(buf, kt)                                                           \
    _Pragma("unroll")                                                              \
    for (int q_ = 0; q_ < 4; ++q_) {                                               \
      int row_ = q_ * 32 + sr;                                                     \
      gl_lds16(A + (size_t)(bm + row_) * 1024 + (kt) * 64 + gsw,                   \
               &As2[(buf) + row_ * 64 + pch * 8]);                                 \
    }
  #define LOAD_B(kt)                                                               \
    _Pragma("unroll")                                                              \
    for (int q_ = 0; q_ < 4; ++q_) {                                               \
      const float* p_ = Bw + (size_t)(bn + q_ * 32 + sr) * 1024 + (kt) * 64 + gsw; \
      sb[q_][0] = *(const float4*)p_;                                              \
      sb[q_][1] = *(const float4*)(p_ + 4);                                        \
    }
  #define CVT_B(buf)                                                               \
    _Pragma("unroll")                                                              \
    for (int q_ = 0; q_ < 4; ++q_) {                                               \
      uint4 w_;                                                                    \
      w_.x = cvtpk(sb[q_][0].x, sb[q_][0].y);                                      \
      w_.y = cvtpk(sb[q_][0].z, sb[q_][0].w);                                      \
      w_.z = cvtpk(sb[q_][1].x, sb[q_][1].y);                                      \
      w_.w = cvtpk(sb[q_][1].z, sb[q_][1].w);                                      \
      *(uint4*)&Bs2[(buf) + (q_ * 32 + sr) * 64 + pch * 8] = w_;                   \
    }

  STG_A(0, 0);
  LOAD_B(0);
  CVT_B(0);
  __syncthreads();

  for (int kt = 0; kt < 16; ++kt) {
    const int bc = (kt & 1) * 8192;
    const int bx = bc ^ 8192;
    if (kt < 15) { STG_A(bx, kt + 1); LOAD_B(kt + 1); }

    #pragma unroll
    for (int ks = 0; ks < 2; ++ks) {
      bf16x8v af[4], bfr[4];
      #pragma unroll
      for (int mi = 0; mi < 4; ++mi)
        af[mi] = *(const bf16x8v*)&As2[bc + (wr * 64 + mi * 16 + c) * 64 + ((ks * 4 + g) ^ cs) * 8];
      #pragma unroll
      for (int ni = 0; ni < 4; ++ni)
        bfr[ni] = *(const bf16x8v*)&Bs2[bc + (wc * 64 + ni * 16 + c) * 64 + ((ks * 4 + g) ^ cs) * 8];
      __builtin_amdgcn_s_setprio(1);
      #pragma unroll
      for (int mi = 0; mi < 4; ++mi)
        #pragma unroll
        for (int ni = 0; ni < 4; ++ni)
          acc[mi][ni] = __builtin_amdgcn_mfma_f32_16x16x32_bf16(af[mi], bfr[ni], acc[mi][ni], 0, 0, 0);
      __builtin_amdgcn_s_setprio(0);
    }
    if (kt < 15) {
      __builtin_amdgcn_sched_barrier(0);
      CVT_B(bx);
    }
    __syncthreads();   // drains gl_lds vmcnt (had full compute phase) + ds writes
  }
  #undef STG_A
  #undef LOAD_B
  #undef CVT_B

  #pragma unroll
  for (int mi = 0; mi < 4; ++mi)
    #pragma unroll
    for (int ni = 0; ni < 4; ++ni)
      #pragma unroll
      for (int j = 0; j < 4; ++j) {
        int gm = bm + wr * 64 + mi * 16 + 4 * g + j;
        int gn = bn + wc * 64 + ni * 16 + c;
        Cout[(size_t)gm * 1024 + gn] = acc[mi][ni][j];
      }
}

// ---------------------------------------------------------------------------
// flash attention, swapped QK^T, max-free softmax (round-4 known-good)
__global__ __launch_bounds__(256) void attn_kernel(const u16* __restrict__ Q, const u16* __restrict__ Kc,
                                                   const u16* __restrict__ Vt,
                                                   const uint32_t* __restrict__ Mw,
                                                   u16* __restrict__ AO)
{
  const int bid = blockIdx.x;
  const int grp = bid & 63;           // (b,h) group; XCD = bid%8 = grp%8
  const int qt  = bid >> 6;
  const int h = grp & 15, b = grp >> 4;
  const int q0 = qt * 64;
  const int tid = threadIdx.x, lane = tid & 63, wave = tid >> 6;
  const int g = lane >> 4, c = lane & 15;
  const int qw = q0 + wave * 16;

  __shared__ __align__(16) u16 Ks[64 * 64];      // 8 KB
  __shared__ __align__(16) u16 Vs[64 * 64];      // 8 KB  [d][l]
  __shared__ __align__(16) u16 Ps[4][16 * 72];   // 9 KB  per-wave P, padded

  bf16x8v qf0, qf1;
  {
    const u16* qp = Q + (size_t)(b * 1024 + qw + c) * 1024 + h * 64 + g * 8;
    qf0 = *(const bf16x8v*)qp;
    qf1 = *(const bf16x8v*)(qp + 32);
  }
  f32x4 zf = {0.f, 0.f, 0.f, 0.f};
  f32x4 O[4];                       // O^T frag: [d=dt*16+4g+j][q=c]
  float l = 0.f;                    // per-lane partial denominator
  #pragma unroll
  for (int dt = 0; dt < 4; ++dt) O[dt] = zf;

  const int sr  = tid >> 3;         // 0..31
  const int pch = tid & 7;
  const int swz = (pch ^ (sr & 7)) * 8;   // write-side XOR swizzle
  const int cs  = c & 7;
  const u16* Kbase = Kc + (size_t)(b * 1536) * 1024 + h * 64;
  const u16* Vbase = Vt + (size_t)(b * 1024 + h * 64) * 1536;
  const uint32_t* mrow = Mw + (size_t)(b * 1024 + qw + c) * 48;

  bf16x8v kr0, kr1, vr0, vr1;
  kr0 = *(const bf16x8v*)(Kbase + (size_t)sr * 1024 + pch * 8);
  kr1 = *(const bf16x8v*)(Kbase + (size_t)(32 + sr) * 1024 + pch * 8);
  vr0 = *(const bf16x8v*)(Vbase + (size_t)sr * 1536 + pch * 8);
  vr1 = *(const bf16x8v*)(Vbase + (size_t)(32 + sr) * 1536 + pch * 8);
  *(bf16x8v*)&Ks[sr * 64 + swz]        = kr0;
  *(bf16x8v*)&Ks[(32 + sr) * 64 + swz] = kr1;
  *(bf16x8v*)&Vs[sr * 64 + swz]        = vr0;
  *(bf16x8v*)&Vs[(32 + sr) * 64 + swz] = vr1;
  __syncthreads();

  for (int kt = 0; kt < 24; ++kt) {
    if (kt < 23) {
      const int ln = (kt + 1) * 64;
      kr0 = *(const bf16x8v*)(Kbase + (size_t)(ln + sr) * 1024 + pch * 8);
      kr1 = *(const bf16x8v*)(Kbase + (size_t)(ln + 32 + sr) * 1024 + pch * 8);
      vr0 = *(const bf16x8v*)(Vbase + (size_t)sr * 1536 + ln + pch * 8);
      vr1 = *(const bf16x8v*)(Vbase + (size_t)(32 + sr) * 1536 + ln + pch * 8);
    }
    uint2 mwv = *(const uint2*)(mrow + kt * 2);

    f32x4 s[4];
    __builtin_amdgcn_s_setprio(1);
    #pragma unroll
    for (int nt = 0; nt < 4; ++nt) {
      const u16* kr = &Ks[(nt * 16 + c) * 64];
      bf16x8v k0 = *(const bf16x8v*)&kr[(g ^ cs) * 8];
      bf16x8v k1 = *(const bf16x8v*)&kr[((4 + g) ^ cs) * 8];
      f32x4 z = zf;
      z = __builtin_amdgcn_mfma_f32_16x16x32_bf16(k0, qf0, z, 0, 0, 0);
      z = __builtin_amdgcn_mfma_f32_16x16x32_bf16(k1, qf1, z, 0, 0, 0);
      s[nt] = z;
    }
    __builtin_amdgcn_s_setprio(0);

    uint64_t mq = (((uint64_t)mwv.y << 32) | (uint64_t)mwv.x) >> (4 * g);
    uint32_t mlo = (uint32_t)mq, mhi = (uint32_t)(mq >> 32);
    #pragma unroll
    for (int nt = 0; nt < 4; ++nt) {
      uint32_t msrc = (nt < 2) ? mlo : mhi;
      #pragma unroll
      for (int j = 0; j < 4; ++j) {
        float e = exp2f(s[nt][j]);
        float p = maskand(e, msrc, 16 * (nt & 1) + j);
        s[nt][j] = p;
        l += p;
      }
    }

    u16* pw = &Ps[wave][0];
    #pragma unroll
    for (int nt = 0; nt < 4; ++nt) {
      uint2 pk2;
      pk2.x = cvtpk(s[nt][0], s[nt][1]);
      pk2.y = cvtpk(s[nt][2], s[nt][3]);
      *(uint2*)&pw[c * 72 + nt * 16 + g * 4] = pk2;
    }
    bf16x8v pb0 = *(const bf16x8v*)&pw[c * 72 + g * 8];
    bf16x8v pb1 = *(const bf16x8v*)&pw[c * 72 + 32 + g * 8];
    __builtin_amdgcn_s_setprio(1);
    #pragma unroll
    for (int dt = 0; dt < 4; ++dt) {
      const u16* vr = &Vs[(dt * 16 + c) * 64];
      bf16x8v v0 = *(const bf16x8v*)&vr[(g ^ cs) * 8];
      bf16x8v v1 = *(const bf16x8v*)&vr[((4 + g) ^ cs) * 8];
      O[dt] = __builtin_amdgcn_mfma_f32_16x16x32_bf16(v0, pb0, O[dt], 0, 0, 0);
      O[dt] = __builtin_amdgcn_mfma_f32_16x16x32_bf16(v1, pb1, O[dt], 0, 0, 0);
    }
    __builtin_amdgcn_s_setprio(0);

    __syncthreads();                 // all waves done READING Ks/Vs
    if (kt < 23) {
      *(bf16x8v*)&Ks[sr * 64 + swz]        = kr0;
      *(bf16x8v*)&Ks[(32 + sr) * 64 + swz] = kr1;
      *(bf16x8v*)&Vs[sr * 64 + swz]        = vr0;
      *(bf16x8v*)&Vs[(32 + sr) * 64 + swz] = vr1;
      __syncthreads();
    }
  }

  float r = l;
  r += __shfl_xor(r, 16);
  r += __shfl_xor(r, 32);
  float inv = 1.f / r;
  size_t ro = (size_t)(b * 1024 + qw + c) * 1024 + h * 64;
  #pragma unroll
  for (int dt = 0; dt < 4; ++dt) {
    uint2 st;
    st.x = cvtpk(O[dt][0] * inv, O[dt][1] * inv);
    st.y = cvtpk(O[dt][2] * inv, O[dt][3] * inv);
    *(uint2*)&AO[ro + dt * 16 + 4 * g] = st;
  }
}

// ---------------------------------------------------------------------------
extern "C" void kernel_launch(void* const* d_in, const int* in_sizes, int n_in,
                              void* d_out, int out_size, void* d_ws, size_t ws_size,
                              hipStream_t stream) {
  (void)in_sizes; (void)n_in; (void)out_size; (void)ws_size;
  const float* hs = (const float*)d_in[0];
  const float* im = (const float*)d_in[1];
  const int*   mk = (const int*)d_in[2];
  const float* wq = (const float*)d_in[3];
  const float* wk = (const float*)d_in[4];
  const float* wv = (const float*)d_in[5];
  const float* uk = (const float*)d_in[6];
  const float* uv = (const float*)d_in[7];
  const float* wo = (const float*)d_in[8];

  char* ws = (char*)d_ws;
  u16* Qb  = (u16*)(ws + 0);          //  8,388,608 B  Q token-major [4096][1024] (pre-scaled)
  u16* Kb  = (u16*)(ws + 8388608);    // 12,582,912 B  K concat [4][1536][1024]
  u16* Vtb = (u16*)(ws + 20971520);   // 12,582,912 B  V transposed [4][1024][1536]
  u16* AO  = (u16*)(ws + 33554432);   //  8,388,608 B  attn out bf16 [4096][1024]
  uint32_t* Mw = (uint32_t*)(ws + 41943040); // 786,432 B packed mask
  // total ws: 42,729,472 B

  gemm_qkv<<<256, 512, 0, stream>>>(hs, im, wq, wk, wv, uk, uv, mk, Qb, Kb, Vtb, Mw);
  attn_kernel<<<1024, 256, 0, stream>>>(Qb, Kb, Vtb, Mw, AO);
  gemm_out<<<256, 256, 0, stream>>>(AO, wo, (float*)d_out);
}